// Round 4
// baseline (990.318 us; speedup 1.0000x reference)
//
#include <hip/hip_runtime.h>
#include <hip/hip_bf16.h>
#include <cstdint>
#include <cstddef>

typedef __hip_bfloat16 bf16;
typedef __attribute__((ext_vector_type(8))) short short8;
typedef __attribute__((ext_vector_type(4))) float floatx4;

#define Bsz 16
#define Lseq 4096
#define Hd 256
#define NM 32          // complex modes per channel
#define NMO 4          // modes per lane after 8-way split
#define NCH 16         // chunks
#define TCH 256        // chunk length (NCH*TCH == Lseq)
#define Mtot (Bsz*Lseq)
#define CSTRIDE (2*NM*Hd)   // 16384 floats per component plane

__device__ __forceinline__ float gelu_tanh(float y) {
  // 0.5*y*(1+tanh(0.79788456*(y+0.044715*y^3))) == y*sigmoid(1.5957691*(y+0.044715*y^3))
  float y2 = y * y;
  float q = fmaf(0.044715f, y2, 1.0f);
  float a = 1.5957691216057308f * y * q;
  float e = __expf(-a);
  return y * __frcp_rn(1.0f + e);
}

// ---------------- K0: per-(dir,d,n) constants ----------------
// cst planes: 0=wr 1=wi 2=Cr 3=Ci 4=wTr 5=wTi ; idx = dir*8192 + n*256 + d
__global__ __launch_bounds__(256) void k_const(
    const float* __restrict__ ldt_fw, const float* __restrict__ lar_fw,
    const float* __restrict__ ai_fw,  const float* __restrict__ C_fw,
    const float* __restrict__ ldt_bw, const float* __restrict__ lar_bw,
    const float* __restrict__ ai_bw,  const float* __restrict__ C_bw,
    float* __restrict__ cst) {
  int t = blockIdx.x * 256 + threadIdx.x;       // 16384 total
  int d = t & 255, n = (t >> 8) & 31, dir = t >> 13;
  const float* ldt = dir ? ldt_bw : ldt_fw;
  const float* lar = dir ? lar_bw : lar_fw;
  const float* ai  = dir ? ai_bw  : ai_fw;
  const float* C   = dir ? C_bw   : C_fw;

  float dt = expf(ldt[d]);
  float Ar = -expf(lar[d * NM + n]);
  float Ai = ai[d * NM + n];
  float cr = C[(d * NM + n) * 2 + 0];
  float ci = C[(d * NM + n) * 2 + 1];

  float er = expf(Ar * dt);
  float sn, cs;
  sincosf(Ai * dt, &sn, &cs);
  float wr = er * cs, wi = er * sn;
  // Ceff = 2*Cc*(w-1)/(A+1e-8)
  float nr = wr - 1.f, ni = wi;
  float tr = cr * nr - ci * ni;
  float ti = cr * ni + ci * nr;
  float dr = Ar + 1e-8f, di = Ai;
  float inv = 1.f / (dr * dr + di * di);
  float Cr = 2.f * (tr * dr + ti * di) * inv;
  float Ci = 2.f * (ti * dr - tr * di) * inv;
  // wT = w^TCH
  float erT = expf((float)TCH * Ar * dt);
  float snT, csT;
  sincosf((float)TCH * Ai * dt, &snT, &csT);
  float wTr = erT * csT, wTi = erT * snT;

  int base = dir * (NM * Hd) + n * Hd + d;
  cst[0 * CSTRIDE + base] = wr;
  cst[1 * CSTRIDE + base] = wi;
  cst[2 * CSTRIDE + base] = Cr;
  cst[3 * CSTRIDE + base] = Ci;
  cst[4 * CSTRIDE + base] = wTr;
  cst[5 * CSTRIDE + base] = wTi;
}

// ---------------- K0b: conv_w fp32 -> bf16 ----------------
__global__ __launch_bounds__(256) void k_wconv(
    const float* __restrict__ W, bf16* __restrict__ Wb, int n) {
  int i = blockIdx.x * 256 + threadIdx.x;
  if (i < n) Wb[i] = __float2bfloat16(W[i]);
}

// ---------------- K1: chunk-local end states ----------------
// 512 threads: blockIdx.z = dir*4+quarter; d = quarter*64 + (tid>>3);
// h = tid&7 owns modes [h*4, h*4+4).
// 8-way split keeps persistent state (~30 floats) far below any register
// budget the allocator picks -> no AGPR spill/shuttle (rounds 0-3 pathology).
// Sloc layout: [b][dir][c][n2(64)][d]  (n2 = 2n for re, 2n+1 for im)
__global__ __launch_bounds__(512, 8) void k_scan1(
    const float* __restrict__ x, const float* __restrict__ cst,
    float* __restrict__ Sloc) {
  const int c = blockIdx.x, b = blockIdx.y;
  const int dir = blockIdx.z >> 2, quarter = blockIdx.z & 3;
  const int d = quarter * 64 + (threadIdx.x >> 3), h = threadIdx.x & 7;
  const int nbase = h * NMO;
  float wr[NMO], wi[NMO], sr[NMO], si[NMO];
  const float* cw = cst + dir * (NM * Hd) + d;
#pragma unroll
  for (int n = 0; n < NMO; ++n) {
    wr[n] = cw[(nbase + n) * Hd];
    wi[n] = cw[CSTRIDE + (nbase + n) * Hd];
    sr[n] = 0.f; si[n] = 0.f;
  }
  const int l0 = c * TCH;
  const float* xp = x + (size_t)b * Lseq * Hd + d;
  const int stp = dir ? -Hd : Hd;
  int pos = dir ? (Lseq - 1 - l0) : l0;
  const float* px = xp + (size_t)pos * Hd;
  float ua = px[0]; px += stp;
  float ub = px[0]; px += stp;
#pragma unroll 1
  for (int t = 0; t < TCH; ++t) {
    float unew = 0.f;
    if (t + 2 < TCH) unew = px[0];
    px += stp;
    float u = ua;
#pragma unroll
    for (int n = 0; n < NMO; ++n) {
      float t0  = fmaf(wr[n], sr[n], u);
      float nsi = wr[n] * si[n];
      nsi = fmaf(wi[n], sr[n], nsi);
      sr[n] = fmaf(-wi[n], si[n], t0);
      si[n] = nsi;
    }
    ua = ub; ub = unew;
  }
  float* outp = Sloc + (((size_t)(b * 2 + dir) * NCH + c) * 64) * Hd + d;
#pragma unroll
  for (int n = 0; n < NMO; ++n) {
    outp[(2 * (nbase + n)) * Hd]     = sr[n];
    outp[(2 * (nbase + n) + 1) * Hd] = si[n];
  }
}

// ---------------- K2: cross-chunk prefix (in-place on Sloc) ----------------
__global__ __launch_bounds__(256) void k_scan2(
    const float* __restrict__ cst, float* __restrict__ S) {
  const int b = blockIdx.x, dir = blockIdx.y, d = threadIdx.x;
  float wTr[NM], wTi[NM], sr[NM], si[NM];
  const float* cw = cst + dir * (NM * Hd) + d;
#pragma unroll
  for (int n = 0; n < NM; ++n) {
    wTr[n] = cw[4 * CSTRIDE + n * Hd];
    wTi[n] = cw[5 * CSTRIDE + n * Hd];
    sr[n] = 0.f; si[n] = 0.f;
  }
  for (int c = 0; c < NCH; ++c) {
    size_t off = (((size_t)(b * 2 + dir) * NCH + c) * 64) * Hd + d;
    float* p = S + off;
#pragma unroll
    for (int n = 0; n < NM; ++n) {
      float lr = p[(2 * n) * Hd], li = p[(2 * n + 1) * Hd];  // read local
      p[(2 * n) * Hd]     = sr[n];                            // write prefix
      p[(2 * n + 1) * Hd] = si[n];
      float t0  = fmaf(wTr[n], sr[n], lr);
      float nsr = fmaf(-wTi[n], si[n], t0);
      float nsi = fmaf(wTr[n], si[n], li);
      nsi = fmaf(wTi[n], sr[n], nsi);
      sr[n] = nsr; si[n] = nsi;
    }
  }
}

// ---------------- K3: final scan + Dskip + GELU -> Act (bf16) ----------------
// 512 threads: blockIdx.z = dir*4+quarter; d = quarter*64 + (tid>>3);
// h = tid&7 owns modes [h*4, h*4+4).
// Persistent state = 24 floats + temps (~38 VGPR) -> no AGPR spill.
// Partial output projections combined via 3x shfl_xor; all 8 lanes store the
// (identical) value — same-address same-value store is deterministic and
// avoids per-iteration exec masking.
// Act layout: [m = b*L + l][ch] with ch = dir*256 + d, 512 channels
__global__ __launch_bounds__(512, 8) void k_scan3(
    const float* __restrict__ x, const float* __restrict__ cst,
    const float* __restrict__ Sstart, const float* __restrict__ Dskip,
    bf16* __restrict__ Act) {
  const int c = blockIdx.x, b = blockIdx.y;
  const int dir = blockIdx.z >> 2, quarter = blockIdx.z & 3;
  const int d = quarter * 64 + (threadIdx.x >> 3), h = threadIdx.x & 7;
  const int nbase = h * NMO;
  float wr[NMO], wi[NMO], cr[NMO], ci[NMO], sr[NMO], si[NMO];
  const float* cw = cst + dir * (NM * Hd) + d;
#pragma unroll
  for (int n = 0; n < NMO; ++n) {
    wr[n] = cw[(nbase + n) * Hd];
    wi[n] = cw[CSTRIDE + (nbase + n) * Hd];
    cr[n] = cw[2 * CSTRIDE + (nbase + n) * Hd];
    ci[n] = cw[3 * CSTRIDE + (nbase + n) * Hd];
  }
  const float* sp = Sstart + (((size_t)(b * 2 + dir) * NCH + c) * 64) * Hd + d;
#pragma unroll
  for (int n = 0; n < NMO; ++n) {
    sr[n] = sp[(2 * (nbase + n)) * Hd];
    si[n] = sp[(2 * (nbase + n) + 1) * Hd];
  }
  const float Dk = Dskip[d];
  const int l0 = c * TCH;
  const float* xp = x + (size_t)b * Lseq * Hd + d;
  const int stp = dir ? -Hd : Hd;
  int pos0 = dir ? (Lseq - 1 - l0) : l0;
  const float* px = xp + (size_t)pos0 * Hd;
  float ua = px[0]; px += stp;
  float ub = px[0]; px += stp;
  bf16* apw = Act + (size_t)b * Lseq * 512 + (size_t)pos0 * 512 + dir * 256 + d;
  const ptrdiff_t astp = dir ? -512 : 512;
#pragma unroll 1
  for (int t = 0; t < TCH; ++t) {
    float unew = 0.f;
    if (t + 2 < TCH) unew = px[0];
    px += stp;
    float u = ua;
    float yp = 0.f;
#pragma unroll
    for (int n = 0; n < NMO; ++n) {
      float t0  = fmaf(wr[n], sr[n], u);
      float nsi = wr[n] * si[n];
      nsi = fmaf(wi[n], sr[n], nsi);
      sr[n] = fmaf(-wi[n], si[n], t0);
      si[n] = nsi;
      yp = fmaf(cr[n], sr[n], yp);
      yp = fmaf(-ci[n], si[n], yp);
    }
    yp += __shfl_xor(yp, 1);
    yp += __shfl_xor(yp, 2);
    yp += __shfl_xor(yp, 4);
    float y = fmaf(u, Dk, yp);
    float ge = gelu_tanh(y);
    *apw = __float2bfloat16(ge);
    apw += astp;
    ua = ub; ub = unew;
  }
}

// ---------------- K4: GEMM (M,K=512)x(1024,K) + bias + GLU -> z (fp32, into d_out) ----------------
#define LDK 40  // padded LDS stride in shorts (32 + 8, keeps 16B alignment)
__global__ __launch_bounds__(256) void k_gemm(
    const bf16* __restrict__ Act, const bf16* __restrict__ W,
    const float* __restrict__ bias, float* __restrict__ z) {
  __shared__ __align__(16) short As[128 * LDK];
  __shared__ __align__(16) short Bas[128 * LDK];
  __shared__ __align__(16) short Bgs[128 * LDK];
  const int bi = blockIdx.x, bj = blockIdx.y;
  const int tid = threadIdx.x, lane = tid & 63, wv = tid >> 6;
  const int wm = (wv & 1) * 64, wn = (wv >> 1) * 64;
  const int M0 = bi * 128;
  floatx4 acc_a[4][4], acc_g[4][4];
#pragma unroll
  for (int i = 0; i < 4; ++i)
#pragma unroll
    for (int j = 0; j < 4; ++j) {
      acc_a[i][j] = (floatx4){0.f, 0.f, 0.f, 0.f};
      acc_g[i][j] = (floatx4){0.f, 0.f, 0.f, 0.f};
    }
  const int row2 = tid >> 2;        // 0..63
  const int kc = (tid & 3) * 8;     // 0,8,16,24 (elements)
  const int fr = lane & 15, fk = (lane >> 4) * 8;

  for (int kb = 0; kb < 512; kb += 32) {
#pragma unroll
    for (int r = 0; r < 2; ++r) {
      int rr = row2 + r * 64;
      *(int4*)&As[rr * LDK + kc]  = *(const int4*)&Act[(size_t)(M0 + rr) * 512 + kb + kc];
      *(int4*)&Bas[rr * LDK + kc] = *(const int4*)&W[(size_t)(bj * 128 + rr) * 512 + kb + kc];
      *(int4*)&Bgs[rr * LDK + kc] = *(const int4*)&W[(size_t)(512 + bj * 128 + rr) * 512 + kb + kc];
    }
    __syncthreads();
    short8 af[4], bfa[4], bfg[4];
#pragma unroll
    for (int i = 0; i < 4; ++i) af[i]  = *(const short8*)&As[(wm + 16 * i + fr) * LDK + fk];
#pragma unroll
    for (int j = 0; j < 4; ++j) bfa[j] = *(const short8*)&Bas[(wn + 16 * j + fr) * LDK + fk];
#pragma unroll
    for (int j = 0; j < 4; ++j) bfg[j] = *(const short8*)&Bgs[(wn + 16 * j + fr) * LDK + fk];
#pragma unroll
    for (int i = 0; i < 4; ++i)
#pragma unroll
      for (int j = 0; j < 4; ++j) {
        acc_a[i][j] = __builtin_amdgcn_mfma_f32_16x16x32_bf16(af[i], bfa[j], acc_a[i][j], 0, 0, 0);
        acc_g[i][j] = __builtin_amdgcn_mfma_f32_16x16x32_bf16(af[i], bfg[j], acc_g[i][j], 0, 0, 0);
      }
    __syncthreads();
  }
  // epilogue: bias + GLU, write z[m][o] fp32, o in [0,512)
  const int col = lane & 15, rquad = (lane >> 4) * 4;
#pragma unroll
  for (int j = 0; j < 4; ++j) {
    int o = bj * 128 + wn + 16 * j + col;
    float ba = bias[o];
    float bg = bias[512 + o];
#pragma unroll
    for (int i = 0; i < 4; ++i) {
      int mbase = M0 + wm + 16 * i + rquad;
#pragma unroll
      for (int rg = 0; rg < 4; ++rg) {
        float a = acc_a[i][j][rg] + ba;
        float g = acc_g[i][j][rg] + bg;
        float zv = a * __frcp_rn(1.f + __expf(-g));
        z[(size_t)(mbase + rg) * 512 + o] = zv;
      }
    }
  }
}

// ---------------- K5: LayerNorm over 512 (in-place on d_out, fp32) ----------------
__global__ __launch_bounds__(256) void k_ln(
    float* __restrict__ z, const float* __restrict__ gamma,
    const float* __restrict__ beta) {
  const int m = blockIdx.x * 4 + (threadIdx.x >> 6);
  const int lane = threadIdx.x & 63;
  float* zp = z + (size_t)m * 512;
  float v[8], s = 0.f, sq = 0.f;
#pragma unroll
  for (int j = 0; j < 8; ++j) {
    v[j] = zp[j * 64 + lane];
    s += v[j];
    sq = fmaf(v[j], v[j], sq);
  }
#pragma unroll
  for (int off = 32; off > 0; off >>= 1) {
    s += __shfl_xor(s, off);
    sq += __shfl_xor(sq, off);
  }
  float mean = s * (1.f / 512.f);
  float var = fmaf(-mean, mean, sq * (1.f / 512.f));
  float inv = rsqrtf(var + 1e-5f);
#pragma unroll
  for (int j = 0; j < 8; ++j) {
    int cidx = j * 64 + lane;
    float g = gamma[cidx], be = beta[cidx];
    zp[cidx] = fmaf((v[j] - mean) * inv, g, be);
  }
}

extern "C" void kernel_launch(void* const* d_in, const int* in_sizes, int n_in,
                              void* d_out, int out_size, void* d_ws, size_t ws_size,
                              hipStream_t stream) {
  const float* x      = (const float*)d_in[0];
  const float* ldt_fw = (const float*)d_in[1];
  const float* lar_fw = (const float*)d_in[2];
  const float* ai_fw  = (const float*)d_in[3];
  const float* C_fw   = (const float*)d_in[4];
  const float* ldt_bw = (const float*)d_in[5];
  const float* lar_bw = (const float*)d_in[6];
  const float* ai_bw  = (const float*)d_in[7];
  const float* C_bw   = (const float*)d_in[8];
  const float* Dskip  = (const float*)d_in[9];
  const float* W      = (const float*)d_in[10];
  const float* bias   = (const float*)d_in[11];
  const float* gamma  = (const float*)d_in[12];
  const float* beta   = (const float*)d_in[13];
  float* out = (float*)d_out;

  char* wsb = (char*)d_ws;
  float* cst  = (float*)wsb;                       // 393,216 B (pad to 512K)
  bf16*  Wb   = (bf16*)(wsb + 524288);             // 1,048,576 B
  float* Sloc = (float*)(wsb + 524288 + 1048576);  // 33,554,432 B
  bf16*  Act  = (bf16*)(wsb + 524288 + 1048576 + 33554432u); // 67,108,864 B
  // total ws: ~102 MB

  k_const<<<dim3(64), dim3(256), 0, stream>>>(ldt_fw, lar_fw, ai_fw, C_fw,
                                              ldt_bw, lar_bw, ai_bw, C_bw, cst);
  k_wconv<<<dim3(2048), dim3(256), 0, stream>>>(W, Wb, 1024 * 512);
  k_scan1<<<dim3(NCH, Bsz, 8), dim3(512), 0, stream>>>(x, cst, Sloc);
  k_scan2<<<dim3(Bsz, 2), dim3(256), 0, stream>>>(cst, Sloc);
  k_scan3<<<dim3(NCH, Bsz, 8), dim3(512), 0, stream>>>(x, cst, Sloc, Dskip, Act);
  k_gemm<<<dim3(Mtot / 128, 4), dim3(256), 0, stream>>>(Act, Wb, bias, out);
  k_ln<<<dim3(Mtot / 4), dim3(256), 0, stream>>>(out, gamma, beta);
}

// Round 6
// 637.383 us; speedup vs baseline: 1.5537x; 1.5537x over previous
//
#include <hip/hip_runtime.h>
#include <hip/hip_bf16.h>
#include <cstdint>
#include <cstddef>

typedef __hip_bfloat16 bf16;
typedef __attribute__((ext_vector_type(8))) short short8;
typedef __attribute__((ext_vector_type(4))) float floatx4;
typedef __attribute__((ext_vector_type(16))) float floatx16;
typedef __attribute__((ext_vector_type(8))) _Float16 half8;

#define Bsz 16
#define Lseq 4096
#define Hd 256
#define NM 32          // complex modes per channel
#define NCH 16         // chunks
#define TCH 256        // chunk length (NCH*TCH == Lseq)
#define Mtot (Bsz*Lseq)

__device__ __forceinline__ float gelu_tanh(float y) {
  float y2 = y * y;
  float q = fmaf(0.044715f, y2, 1.0f);
  float a = 1.5957691216057308f * y * q;
  float e = __expf(-a);
  return y * __frcp_rn(1.0f + e);
}

// ---------------- K_prep: per-(dir,d) tables for the matmul formulation ---
// KK[dir][d][512]  fp16: dir0: KK[i]=K[255-i] (i<=255) else 0  (A[t][tau]=KK[255-t+tau])
//                        dir1: KK[i]=K[i-255] (i>=255) else 0
// Vm[dir][d][n2][256] fp16: dir0: Vm[2n][tau]=Re(w^{255-tau}) ; dir1: Re(w^{tau})
// P [dir][d][256][64] fp16: dir0: P[t][2n]=Re(C w^{t+1}), [2n+1]=-Im(C w^{t+1})
//                           dir1: exponent 256-t
// wtb[dir][d][64] fp32: [2n]=Re(w^256), [2n+1]=Im(w^256)
__global__ __launch_bounds__(64) void k_prep(
    const float* __restrict__ ldt_fw, const float* __restrict__ lar_fw,
    const float* __restrict__ ai_fw,  const float* __restrict__ C_fw,
    const float* __restrict__ ldt_bw, const float* __restrict__ lar_bw,
    const float* __restrict__ ai_bw,  const float* __restrict__ C_bw,
    _Float16* __restrict__ Vm, _Float16* __restrict__ P,
    _Float16* __restrict__ KK, float* __restrict__ wtb) {
  const int d = blockIdx.x, dir = blockIdx.y;
  const int lane = threadIdx.x;
  const int n = lane & 31;
  const bool active = lane < 32;
  const float* ldt = dir ? ldt_bw : ldt_fw;
  const float* lar = dir ? lar_bw : lar_fw;
  const float* ai  = dir ? ai_bw  : ai_fw;
  const float* C   = dir ? C_bw   : C_fw;

  float dt = expf(ldt[d]);
  float Ar = -expf(lar[d * NM + n]);
  float Ai = ai[d * NM + n];
  float c0 = C[(d * NM + n) * 2 + 0];
  float c1 = C[(d * NM + n) * 2 + 1];

  float er = expf(Ar * dt);
  float sn, cs;
  sincosf(Ai * dt, &sn, &cs);
  float wr = er * cs, wi = er * sn;
  // Ceff = 2*Cc*(w-1)/(A+1e-8)
  float nr = wr - 1.f, ni = wi;
  float tr_ = c0 * nr - c1 * ni;
  float ti  = c0 * ni + c1 * nr;
  float dr = Ar + 1e-8f, di = Ai;
  float inv = 1.f / (dr * dr + di * di);
  float Cr = 2.f * (tr_ * dr + ti * di) * inv;
  float Ci = 2.f * (ti * dr - tr_ * di) * inv;
  // wT = w^256 (direct exp for accuracy)
  float erT = expf(256.f * Ar * dt);
  float snT, csT;
  sincosf(256.f * Ai * dt, &snT, &csT);
  if (active) {
    wtb[(dir * 256 + d) * 64 + 2 * n]     = erT * csT;
    wtb[(dir * 256 + d) * 64 + 2 * n + 1] = erT * snT;
  }
  // zero KK
  _Float16* kk = KK + (dir * 256 + d) * 512;
  for (int i = lane; i < 512; i += 64) kk[i] = (_Float16)0.f;
  __syncthreads();

  _Float16* vm = Vm + (size_t)(dir * 256 + d) * 64 * 256;
  _Float16* pp = P  + (size_t)(dir * 256 + d) * 256 * 64;
  float pr = 1.f, pi = 0.f;  // w^j
  for (int j = 0; j <= 256; ++j) {
    float kc = active ? (Cr * pr - Ci * pi) : 0.f;
#pragma unroll
    for (int off = 32; off > 0; off >>= 1) kc += __shfl_xor(kc, off);
    if (lane == 0 && j <= 255) {
      int i = dir ? (255 + j) : (255 - j);
      kk[i] = (_Float16)kc;
    }
    if (active) {
      if (j <= 255) {
        int tv = dir ? j : (255 - j);
        vm[(2 * n) * 256 + tv]     = (_Float16)pr;
        vm[(2 * n + 1) * 256 + tv] = (_Float16)pi;
      }
      if (j >= 1) {
        int t = dir ? (256 - j) : (j - 1);
        float cwr = Cr * pr - Ci * pi;
        float cwi = Cr * pi + Ci * pr;
        pp[t * 64 + 2 * n]     = (_Float16)cwr;
        pp[t * 64 + 2 * n + 1] = (_Float16)(-cwi);
      }
    }
    float npr = pr * wr - pi * wi;
    float npi = pr * wi + pi * wr;
    pr = npr; pi = npi;
  }
}

// ---------------- K0b: conv_w fp32 -> bf16 ----------------
__global__ __launch_bounds__(256) void k_wconv(
    const float* __restrict__ W, bf16* __restrict__ Wb, int n) {
  int i = blockIdx.x * 256 + threadIdx.x;
  if (i < n) Wb[i] = __float2bfloat16(W[i]);
}

// ---------------- K_tr: x[m=b*L+l][d] fp32 -> x16[d][m] fp16 ------------
__global__ __launch_bounds__(256) void k_tr(
    const float* __restrict__ x, _Float16* __restrict__ x16) {
  __shared__ __align__(16) _Float16 t16[64][72];
  const int m0 = blockIdx.x * 64, d0 = blockIdx.y * 64;
  const int tid = threadIdx.x;
  {
    int li = tid >> 2, dq = (tid & 3) * 16;
    const float* src = x + (size_t)(m0 + li) * 256 + d0 + dq;
    float4 v0 = ((const float4*)src)[0];
    float4 v1 = ((const float4*)src)[1];
    float4 v2 = ((const float4*)src)[2];
    float4 v3 = ((const float4*)src)[3];
    half8 h0, h1;
    h0[0]=(_Float16)v0.x; h0[1]=(_Float16)v0.y; h0[2]=(_Float16)v0.z; h0[3]=(_Float16)v0.w;
    h0[4]=(_Float16)v1.x; h0[5]=(_Float16)v1.y; h0[6]=(_Float16)v1.z; h0[7]=(_Float16)v1.w;
    h1[0]=(_Float16)v2.x; h1[1]=(_Float16)v2.y; h1[2]=(_Float16)v2.z; h1[3]=(_Float16)v2.w;
    h1[4]=(_Float16)v3.x; h1[5]=(_Float16)v3.y; h1[6]=(_Float16)v3.z; h1[7]=(_Float16)v3.w;
    *(half8*)&t16[li][dq] = h0;
    *(half8*)&t16[li][dq + 8] = h1;
  }
  __syncthreads();
  {
    int dj = tid >> 2, lq = (tid & 3) * 16;
    half8 o0, o1;
#pragma unroll
    for (int i = 0; i < 8; ++i) {
      o0[i] = t16[lq + i][dj];
      o1[i] = t16[lq + 8 + i][dj];
    }
    _Float16* dst = x16 + (size_t)(d0 + dj) * 65536 + m0 + lq;
    ((half8*)dst)[0] = o0;
    ((half8*)dst)[1] = o1;
  }
}

// ---------------- K_mm1: chunk-local states L = Vm @ u ------------------
// one wg per (d, dir); 256 thr = 4 waves, wave wv owns 64 cols (col=b*16+c)
// Sloc_T layout: [b][dir][c][d][n2(64)] fp32
__global__ __launch_bounds__(256) void k_mm1(
    const _Float16* __restrict__ x16, const _Float16* __restrict__ Vm,
    float* __restrict__ Sloc) {
  const int d = blockIdx.x, dir = blockIdx.y;
  const int tid = threadIdx.x, lane = tid & 63, wv = tid >> 6;
  __shared__ __align__(16) _Float16 ub[256][24];  // 16 tau + 8 pad
  floatx16 acc[2][2];
#pragma unroll
  for (int a = 0; a < 2; ++a)
#pragma unroll
    for (int b = 0; b < 2; ++b)
#pragma unroll
      for (int i = 0; i < 16; ++i) acc[a][b][i] = 0.f;

  const _Float16* vmp = Vm + (size_t)(dir * 256 + d) * 64 * 256;
  const int arow = lane & 31, ak = (lane >> 5) * 8;
  const int colb = wv * 64;

  for (int ks = 0; ks < 16; ++ks) {
    const int tau0 = ks * 16;
    __syncthreads();
    {
      int col = tid;
      int b = col >> 4, c = col & 15;
      const _Float16* up = x16 + (size_t)d * 65536 + b * 4096 + c * 256 + tau0;
      ((int4*)&ub[col][0])[0] = ((const int4*)up)[0];
      ((int4*)&ub[col][0])[1] = ((const int4*)up)[1];
    }
    __syncthreads();
    half8 a0 = *(const half8*)(vmp + (size_t)(0 * 32 + arow) * 256 + tau0 + ak);
    half8 a1 = *(const half8*)(vmp + (size_t)(1 * 32 + arow) * 256 + tau0 + ak);
    half8 b0 = *(const half8*)&ub[colb + arow][ak];
    half8 b1 = *(const half8*)&ub[colb + 32 + arow][ak];
    acc[0][0] = __builtin_amdgcn_mfma_f32_32x32x16_f16(a0, b0, acc[0][0], 0, 0, 0);
    acc[0][1] = __builtin_amdgcn_mfma_f32_32x32x16_f16(a0, b1, acc[0][1], 0, 0, 0);
    acc[1][0] = __builtin_amdgcn_mfma_f32_32x32x16_f16(a1, b0, acc[1][0], 0, 0, 0);
    acc[1][1] = __builtin_amdgcn_mfma_f32_32x32x16_f16(a1, b1, acc[1][1], 0, 0, 0);
  }
  const int hi = lane >> 5;
#pragma unroll
  for (int rt = 0; rt < 2; ++rt)
#pragma unroll
    for (int ct = 0; ct < 2; ++ct) {
      int coll = colb + ct * 32 + (lane & 31);
      int b = coll >> 4, c = coll & 15;
      float* sp = Sloc + ((((size_t)(b * 2 + dir)) * 16 + c) * 256 + d) * 64;
#pragma unroll
      for (int r = 0; r < 16; r += 2) {
        int n2 = (r & 3) + 8 * (r >> 2) + 4 * hi + rt * 32;
        float2 v;
        v.x = acc[rt][ct][r];
        v.y = acc[rt][ct][r + 1];
        *(float2*)(sp + n2) = v;
      }
    }
}

// ---------------- K_scan2: cross-chunk prefix (in-place on Sloc_T) ------
// grid (Bsz, 2, 4): d = bz*64 + tid>>2, h = tid&3 owns modes [h*8,h*8+8)
// dir0: chunks 0..15 ; dir1: chunks 15..0 (spatial chunk index both dirs)
__global__ __launch_bounds__(256) void k_scan2(
    const float* __restrict__ wtb, float* __restrict__ S) {
  const int b = blockIdx.x, dir = blockIdx.y;
  const int d = blockIdx.z * 64 + (threadIdx.x >> 2), h = threadIdx.x & 3;
  const int nbase = h * 8;
  float wTr[8], wTi[8], sr[8], si[8];
  const float* wt = wtb + (dir * 256 + d) * 64;
#pragma unroll
  for (int n = 0; n < 8; ++n) {
    wTr[n] = wt[2 * (nbase + n)];
    wTi[n] = wt[2 * (nbase + n) + 1];
    sr[n] = 0.f; si[n] = 0.f;
  }
  for (int cc = 0; cc < NCH; ++cc) {
    int c = dir ? (NCH - 1 - cc) : cc;
    float* p = S + ((((size_t)(b * 2 + dir)) * 16 + c) * 256 + d) * 64;
#pragma unroll
    for (int n = 0; n < 8; ++n) {
      int n2 = 2 * (nbase + n);
      float lr = p[n2], li = p[n2 + 1];
      p[n2] = sr[n]; p[n2 + 1] = si[n];
      float t0  = fmaf(wTr[n], sr[n], lr);
      float nsr = fmaf(-wTi[n], si[n], t0);
      float nsi = fmaf(wTr[n], si[n], li);
      nsi = fmaf(wTi[n], sr[n], nsi);
      sr[n] = nsr; si[n] = nsi;
    }
  }
}

// ---------------- K_mm2: Y = Toeplitz(K)@u + P@S + Dk*u, GELU -> ActT ---
// one wg per (d, dir); 512 thr = 8 waves; wave wv owns t rows [wv*32,+32)
// ActT layout: [ch = dir*256+d][m = b*4096 + c*256 + t] bf16
__global__ __launch_bounds__(512) void k_mm2(
    const _Float16* __restrict__ x16, const _Float16* __restrict__ KK,
    const _Float16* __restrict__ P, const float* __restrict__ Sstart,
    const float* __restrict__ Dskip, bf16* __restrict__ ActT) {
  const int d = blockIdx.x, dir = blockIdx.y;
  const int tid = threadIdx.x, lane = tid & 63, wv = tid >> 6;
  __shared__ __align__(16) _Float16 ub[64][272];   // [col][256 tau + 16 pad]
  __shared__ __align__(16) _Float16 sb[64][72];    // [col][64 n2 + 8 pad]
  __shared__ __align__(16) _Float16 kks[8][520];   // 8 shifted copies

  // stage shifted KK copies: kks[r][x] = KK[x+r] (zero-padded)
  {
    const _Float16* kg = KK + (dir * 256 + d) * 512;
#pragma unroll
    for (int rr = 0; rr < 8; ++rr)
      for (int xx = tid; xx < 520; xx += 512) {
        int s = xx + rr;
        kks[rr][xx] = (s < 512) ? kg[s] : (_Float16)0.f;
      }
  }
  const float Dk = Dskip[d];
  const int t = wv * 32 + (lane & 31);
  const int hi = lane >> 5;
  const int r_sh = (255 - t) & 7;
  const _Float16* pp = P + (size_t)(dir * 256 + d) * 256 * 64 + (size_t)t * 64;

  for (int cb = 0; cb < 4; ++cb) {
    __syncthreads();
    {  // stage u: 64 cols x 256 tau (32 halves = 4 x int4 per (col,part))
      int col = tid >> 3, part = tid & 7;
      int coll = cb * 64 + col;
      int b = coll >> 4, c = coll & 15;
      const _Float16* up = x16 + (size_t)d * 65536 + b * 4096 + c * 256 + part * 32;
      ((int4*)&ub[col][part * 32])[0] = ((const int4*)up)[0];
      ((int4*)&ub[col][part * 32])[1] = ((const int4*)up)[1];
      ((int4*)&ub[col][part * 32])[2] = ((const int4*)up)[2];
      ((int4*)&ub[col][part * 32])[3] = ((const int4*)up)[3];
    }
    {  // stage S: 64 cols x 64 n2 (fp32 -> fp16)
      int col = tid >> 3, part = tid & 7;
      int coll = cb * 64 + col;
      int b = coll >> 4, c = coll & 15;
      const float* sp = Sstart + ((((size_t)(b * 2 + dir)) * 16 + c) * 256 + d) * 64 + part * 8;
      float4 f0 = ((const float4*)sp)[0];
      float4 f1 = ((const float4*)sp)[1];
      half8 hv;
      hv[0]=(_Float16)f0.x; hv[1]=(_Float16)f0.y; hv[2]=(_Float16)f0.z; hv[3]=(_Float16)f0.w;
      hv[4]=(_Float16)f1.x; hv[5]=(_Float16)f1.y; hv[6]=(_Float16)f1.z; hv[7]=(_Float16)f1.w;
      *(half8*)&sb[col][part * 8] = hv;
    }
    __syncthreads();

    floatx16 acc0, acc1;
#pragma unroll
    for (int i = 0; i < 16; ++i) { acc0[i] = 0.f; acc1[i] = 0.f; }

    // conv: Y += Toeplitz @ u   (A[t][tau] = KK[255 - t + tau])
#pragma unroll
    for (int ks = 0; ks < 16; ++ks) {
      int i0 = 255 - t + ks * 16 + hi * 8;
      half8 af = *(const half8*)&kks[r_sh][i0 - r_sh];
      half8 b0 = *(const half8*)&ub[(lane & 31)][ks * 16 + hi * 8];
      half8 b1 = *(const half8*)&ub[32 + (lane & 31)][ks * 16 + hi * 8];
      acc0 = __builtin_amdgcn_mfma_f32_32x32x16_f16(af, b0, acc0, 0, 0, 0);
      acc1 = __builtin_amdgcn_mfma_f32_32x32x16_f16(af, b1, acc1, 0, 0, 0);
    }
    // boundary: Y += P @ S
#pragma unroll
    for (int ks = 0; ks < 4; ++ks) {
      half8 af = *(const half8*)(pp + ks * 16 + hi * 8);
      half8 b0 = *(const half8*)&sb[(lane & 31)][ks * 16 + hi * 8];
      half8 b1 = *(const half8*)&sb[32 + (lane & 31)][ks * 16 + hi * 8];
      acc0 = __builtin_amdgcn_mfma_f32_32x32x16_f16(af, b0, acc0, 0, 0, 0);
      acc1 = __builtin_amdgcn_mfma_f32_32x32x16_f16(af, b1, acc1, 0, 0, 0);
    }
    // epilogue: skip + gelu -> ActT (packed 2x bf16 per dword store)
#pragma unroll
    for (int ct = 0; ct < 2; ++ct) {
      int coll = cb * 64 + ct * 32 + (lane & 31);
      int b = coll >> 4, c = coll & 15;
      bf16* op = ActT + (size_t)(dir * 256 + d) * 65536 + b * 4096 + c * 256;
      int ucol = ct * 32 + (lane & 31);
#pragma unroll
      for (int r = 0; r < 16; r += 2) {
        int tt = (r & 3) + 8 * (r >> 2) + 4 * hi + wv * 32;
        float a0 = (ct ? acc1[r] : acc0[r]);
        float a1 = (ct ? acc1[r + 1] : acc0[r + 1]);
        float u0 = (float)ub[ucol][tt];
        float u1 = (float)ub[ucol][tt + 1];
        float g0 = gelu_tanh(fmaf(u0, Dk, a0));
        float g1 = gelu_tanh(fmaf(u1, Dk, a1));
        bf16 h0 = __float2bfloat16(g0);
        bf16 h1 = __float2bfloat16(g1);
        unsigned pk = (unsigned)*(unsigned short*)&h0 |
                      ((unsigned)*(unsigned short*)&h1 << 16);
        *(unsigned*)(op + tt) = pk;
      }
    }
  }
}

// ---------------- K_tr2: ActT[ch][m] -> Act[m][ch] (bf16) ---------------
__global__ __launch_bounds__(256) void k_tr2(
    const bf16* __restrict__ AT, bf16* __restrict__ A) {
  __shared__ __align__(16) short tl[64][72];
  const int m0 = blockIdx.x * 64, ch0 = blockIdx.y * 64;
  const int tid = threadIdx.x;
  {
    int chi = tid >> 2, mq = (tid & 3) * 16;
    const short* src = (const short*)AT + (size_t)(ch0 + chi) * 65536 + m0 + mq;
    *(int4*)&tl[chi][mq] = ((const int4*)src)[0];
    *(int4*)&tl[chi][mq + 8] = ((const int4*)src)[1];
  }
  __syncthreads();
  {
    int mi = tid >> 2, chq = (tid & 3) * 16;
    short8 s0, s1;
#pragma unroll
    for (int i = 0; i < 8; ++i) {
      s0[i] = tl[chq + i][mi];
      s1[i] = tl[chq + 8 + i][mi];
    }
    short* dst = (short*)A + (size_t)(m0 + mi) * 512 + ch0 + chq;
    ((short8*)dst)[0] = s0;
    ((short8*)dst)[1] = s1;
  }
}

// ---------------- K4: GEMM (M,K=512)x(1024,K) + bias + GLU -> z ---------
#define LDK 40
__global__ __launch_bounds__(256) void k_gemm(
    const bf16* __restrict__ Act, const bf16* __restrict__ W,
    const float* __restrict__ bias, float* __restrict__ z) {
  __shared__ __align__(16) short As[128 * LDK];
  __shared__ __align__(16) short Bas[128 * LDK];
  __shared__ __align__(16) short Bgs[128 * LDK];
  const int bi = blockIdx.x, bj = blockIdx.y;
  const int tid = threadIdx.x, lane = tid & 63, wv = tid >> 6;
  const int wm = (wv & 1) * 64, wn = (wv >> 1) * 64;
  const int M0 = bi * 128;
  floatx4 acc_a[4][4], acc_g[4][4];
#pragma unroll
  for (int i = 0; i < 4; ++i)
#pragma unroll
    for (int j = 0; j < 4; ++j) {
      acc_a[i][j] = (floatx4){0.f, 0.f, 0.f, 0.f};
      acc_g[i][j] = (floatx4){0.f, 0.f, 0.f, 0.f};
    }
  const int row2 = tid >> 2;
  const int kc = (tid & 3) * 8;
  const int fr = lane & 15, fk = (lane >> 4) * 8;

  for (int kb = 0; kb < 512; kb += 32) {
#pragma unroll
    for (int r = 0; r < 2; ++r) {
      int rr = row2 + r * 64;
      *(int4*)&As[rr * LDK + kc]  = *(const int4*)&Act[(size_t)(M0 + rr) * 512 + kb + kc];
      *(int4*)&Bas[rr * LDK + kc] = *(const int4*)&W[(size_t)(bj * 128 + rr) * 512 + kb + kc];
      *(int4*)&Bgs[rr * LDK + kc] = *(const int4*)&W[(size_t)(512 + bj * 128 + rr) * 512 + kb + kc];
    }
    __syncthreads();
    short8 af[4], bfa[4], bfg[4];
#pragma unroll
    for (int i = 0; i < 4; ++i) af[i]  = *(const short8*)&As[(wm + 16 * i + fr) * LDK + fk];
#pragma unroll
    for (int j = 0; j < 4; ++j) bfa[j] = *(const short8*)&Bas[(wn + 16 * j + fr) * LDK + fk];
#pragma unroll
    for (int j = 0; j < 4; ++j) bfg[j] = *(const short8*)&Bgs[(wn + 16 * j + fr) * LDK + fk];
#pragma unroll
    for (int i = 0; i < 4; ++i)
#pragma unroll
      for (int j = 0; j < 4; ++j) {
        acc_a[i][j] = __builtin_amdgcn_mfma_f32_16x16x32_bf16(af[i], bfa[j], acc_a[i][j], 0, 0, 0);
        acc_g[i][j] = __builtin_amdgcn_mfma_f32_16x16x32_bf16(af[i], bfg[j], acc_g[i][j], 0, 0, 0);
      }
    __syncthreads();
  }
  const int col = lane & 15, rquad = (lane >> 4) * 4;
#pragma unroll
  for (int j = 0; j < 4; ++j) {
    int o = bj * 128 + wn + 16 * j + col;
    float ba = bias[o];
    float bg = bias[512 + o];
#pragma unroll
    for (int i = 0; i < 4; ++i) {
      int mbase = M0 + wm + 16 * i + rquad;
#pragma unroll
      for (int rg = 0; rg < 4; ++rg) {
        float a = acc_a[i][j][rg] + ba;
        float g = acc_g[i][j][rg] + bg;
        float zv = a * __frcp_rn(1.f + __expf(-g));
        z[(size_t)(mbase + rg) * 512 + o] = zv;
      }
    }
  }
}

// ---------------- K5: LayerNorm over 512 (in-place on d_out) ------------
__global__ __launch_bounds__(256) void k_ln(
    float* __restrict__ z, const float* __restrict__ gamma,
    const float* __restrict__ beta) {
  const int m = blockIdx.x * 4 + (threadIdx.x >> 6);
  const int lane = threadIdx.x & 63;
  float* zp = z + (size_t)m * 512;
  float v[8], s = 0.f, sq = 0.f;
#pragma unroll
  for (int j = 0; j < 8; ++j) {
    v[j] = zp[j * 64 + lane];
    s += v[j];
    sq = fmaf(v[j], v[j], sq);
  }
#pragma unroll
  for (int off = 32; off > 0; off >>= 1) {
    s += __shfl_xor(s, off);
    sq += __shfl_xor(sq, off);
  }
  float mean = s * (1.f / 512.f);
  float var = fmaf(-mean, mean, sq * (1.f / 512.f));
  float inv = rsqrtf(var + 1e-5f);
#pragma unroll
  for (int j = 0; j < 8; ++j) {
    int cidx = j * 64 + lane;
    float g = gamma[cidx], be = beta[cidx];
    zp[cidx] = fmaf((v[j] - mean) * inv, g, be);
  }
}

extern "C" void kernel_launch(void* const* d_in, const int* in_sizes, int n_in,
                              void* d_out, int out_size, void* d_ws, size_t ws_size,
                              hipStream_t stream) {
  const float* x      = (const float*)d_in[0];
  const float* ldt_fw = (const float*)d_in[1];
  const float* lar_fw = (const float*)d_in[2];
  const float* ai_fw  = (const float*)d_in[3];
  const float* C_fw   = (const float*)d_in[4];
  const float* ldt_bw = (const float*)d_in[5];
  const float* lar_bw = (const float*)d_in[6];
  const float* ai_bw  = (const float*)d_in[7];
  const float* C_bw   = (const float*)d_in[8];
  const float* Dskip  = (const float*)d_in[9];
  const float* W      = (const float*)d_in[10];
  const float* bias   = (const float*)d_in[11];
  const float* gamma  = (const float*)d_in[12];
  const float* beta   = (const float*)d_in[13];
  float* out = (float*)d_out;

  // workspace map (bytes):
  //  [0)          ActT   512*65536*2  = 67,108,864
  //  [67108864)   SlocT  16*2*16*256*64*4 = 33,554,432
  //  [100663296)  x16    256*65536*2  = 33,554,432
  //  [134217728)  Vm     2*256*64*256*2 = 16,777,216
  //  [150994944)  P      2*256*256*64*2 = 16,777,216
  //  [167772160)  KK     2*256*512*2  = 524,288
  //  [168296448)  wtb    2*256*64*4   = 131,072
  //  [168427520)  Wb     1,048,576     -> total ~169.5 MB
  //  Act (final [m][ch], 67,108,864 B) aliases [SlocT + x16]; both dead by k_tr2.
  char* wsb = (char*)d_ws;
  bf16*     ActT  = (bf16*)wsb;
  float*    SlocT = (float*)(wsb + 67108864u);
  _Float16* x16   = (_Float16*)(wsb + 100663296u);
  _Float16* Vm    = (_Float16*)(wsb + 134217728u);
  _Float16* P     = (_Float16*)(wsb + 150994944u);
  _Float16* KK    = (_Float16*)(wsb + 167772160u);
  float*    wtb   = (float*)(wsb + 168296448u);
  bf16*     Wb    = (bf16*)(wsb + 168427520u);
  bf16*     Act   = (bf16*)(wsb + 67108864u);   // alias over SlocT+x16

  k_prep<<<dim3(256, 2), dim3(64), 0, stream>>>(
      ldt_fw, lar_fw, ai_fw, C_fw, ldt_bw, lar_bw, ai_bw, C_bw, Vm, P, KK, wtb);
  k_wconv<<<dim3(2048), dim3(256), 0, stream>>>(W, Wb, 1024 * 512);
  k_tr<<<dim3(Mtot / 64, 4), dim3(256), 0, stream>>>(x, x16);
  k_mm1<<<dim3(256, 2), dim3(256), 0, stream>>>(x16, Vm, SlocT);
  k_scan2<<<dim3(Bsz, 2, 4), dim3(256), 0, stream>>>(wtb, SlocT);
  k_mm2<<<dim3(256, 2), dim3(512), 0, stream>>>(x16, KK, P, SlocT, Dskip, ActT);
  k_tr2<<<dim3(Mtot / 64, 8), dim3(256), 0, stream>>>(ActT, Act);
  k_gemm<<<dim3(Mtot / 128, 4), dim3(256), 0, stream>>>(Act, Wb, bias, out);
  k_ln<<<dim3(Mtot / 4), dim3(256), 0, stream>>>(out, gamma, beta);
}

// Round 7
// 532.038 us; speedup vs baseline: 1.8614x; 1.1980x over previous
//
#include <hip/hip_runtime.h>
#include <hip/hip_bf16.h>
#include <cstdint>
#include <cstddef>

typedef __hip_bfloat16 bf16;
typedef __attribute__((ext_vector_type(8))) short short8;
typedef __attribute__((ext_vector_type(4))) float floatx4;
typedef __attribute__((ext_vector_type(16))) float floatx16;
typedef __attribute__((ext_vector_type(8))) _Float16 half8;

#define Bsz 16
#define Lseq 4096
#define Hd 256
#define NM 32          // complex modes per channel
#define NCH 16         // chunks
#define TCH 256        // chunk length (NCH*TCH == Lseq)
#define Mtot (Bsz*Lseq)

__device__ __forceinline__ float gelu_tanh(float y) {
  float y2 = y * y;
  float q = fmaf(0.044715f, y2, 1.0f);
  float a = 1.5957691216057308f * y * q;
  float e = __expf(-a);
  return y * __frcp_rn(1.0f + e);
}

// ---------------- K_prep: per-(dir,d) tables for the matmul formulation ---
// KK[dir][d][512]  fp16: dir0: KK[i]=K[255-i] (i<=255) else 0  (A[t][tau]=KK[255-t+tau])
//                        dir1: KK[i]=K[i-255] (i>=255) else 0
// Vm[dir][d][n2][256] fp16: dir0: Vm[2n][tau]=Re(w^{255-tau}) ; dir1: Re(w^{tau})
// P [dir][d][256][64] fp16: dir0: P[t][2n]=Re(C w^{t+1}), [2n+1]=-Im(C w^{t+1})
//                           dir1: exponent 256-t
// wtb[dir][d][64] fp32: [2n]=Re(w^256), [2n+1]=Im(w^256)
__global__ __launch_bounds__(64) void k_prep(
    const float* __restrict__ ldt_fw, const float* __restrict__ lar_fw,
    const float* __restrict__ ai_fw,  const float* __restrict__ C_fw,
    const float* __restrict__ ldt_bw, const float* __restrict__ lar_bw,
    const float* __restrict__ ai_bw,  const float* __restrict__ C_bw,
    _Float16* __restrict__ Vm, _Float16* __restrict__ P,
    _Float16* __restrict__ KK, float* __restrict__ wtb) {
  const int d = blockIdx.x, dir = blockIdx.y;
  const int lane = threadIdx.x;
  const int n = lane & 31;
  const bool active = lane < 32;
  const float* ldt = dir ? ldt_bw : ldt_fw;
  const float* lar = dir ? lar_bw : lar_fw;
  const float* ai  = dir ? ai_bw  : ai_fw;
  const float* C   = dir ? C_bw   : C_fw;

  float dt = expf(ldt[d]);
  float Ar = -expf(lar[d * NM + n]);
  float Ai = ai[d * NM + n];
  float c0 = C[(d * NM + n) * 2 + 0];
  float c1 = C[(d * NM + n) * 2 + 1];

  float er = expf(Ar * dt);
  float sn, cs;
  sincosf(Ai * dt, &sn, &cs);
  float wr = er * cs, wi = er * sn;
  // Ceff = 2*Cc*(w-1)/(A+1e-8)
  float nr = wr - 1.f, ni = wi;
  float tr_ = c0 * nr - c1 * ni;
  float ti  = c0 * ni + c1 * nr;
  float dr = Ar + 1e-8f, di = Ai;
  float inv = 1.f / (dr * dr + di * di);
  float Cr = 2.f * (tr_ * dr + ti * di) * inv;
  float Ci = 2.f * (ti * dr - tr_ * di) * inv;
  // wT = w^256 (direct exp for accuracy)
  float erT = expf(256.f * Ar * dt);
  float snT, csT;
  sincosf(256.f * Ai * dt, &snT, &csT);
  if (active) {
    wtb[(dir * 256 + d) * 64 + 2 * n]     = erT * csT;
    wtb[(dir * 256 + d) * 64 + 2 * n + 1] = erT * snT;
  }
  // zero KK
  _Float16* kk = KK + (dir * 256 + d) * 512;
  for (int i = lane; i < 512; i += 64) kk[i] = (_Float16)0.f;
  __syncthreads();

  _Float16* vm = Vm + (size_t)(dir * 256 + d) * 64 * 256;
  _Float16* pp = P  + (size_t)(dir * 256 + d) * 256 * 64;
  float pr = 1.f, pi = 0.f;  // w^j
  for (int j = 0; j <= 256; ++j) {
    float kc = active ? (Cr * pr - Ci * pi) : 0.f;
#pragma unroll
    for (int off = 32; off > 0; off >>= 1) kc += __shfl_xor(kc, off);
    if (lane == 0 && j <= 255) {
      int i = dir ? (255 + j) : (255 - j);
      kk[i] = (_Float16)kc;
    }
    if (active) {
      if (j <= 255) {
        int tv = dir ? j : (255 - j);
        vm[(2 * n) * 256 + tv]     = (_Float16)pr;
        vm[(2 * n + 1) * 256 + tv] = (_Float16)pi;
      }
      if (j >= 1) {
        int t = dir ? (256 - j) : (j - 1);
        float cwr = Cr * pr - Ci * pi;
        float cwi = Cr * pi + Ci * pr;
        pp[t * 64 + 2 * n]     = (_Float16)cwr;
        pp[t * 64 + 2 * n + 1] = (_Float16)(-cwi);
      }
    }
    float npr = pr * wr - pi * wi;
    float npi = pr * wi + pi * wr;
    pr = npr; pi = npi;
  }
}

// ---------------- K0b: conv_w fp32 -> bf16 ----------------
__global__ __launch_bounds__(256) void k_wconv(
    const float* __restrict__ W, bf16* __restrict__ Wb, int n) {
  int i = blockIdx.x * 256 + threadIdx.x;
  if (i < n) Wb[i] = __float2bfloat16(W[i]);
}

// ---------------- K_tr: x[m=b*L+l][d] fp32 -> x16[d][m] fp16 ------------
__global__ __launch_bounds__(256) void k_tr(
    const float* __restrict__ x, _Float16* __restrict__ x16) {
  __shared__ __align__(16) _Float16 t16[64][72];
  const int m0 = blockIdx.x * 64, d0 = blockIdx.y * 64;
  const int tid = threadIdx.x;
  {
    int li = tid >> 2, dq = (tid & 3) * 16;
    const float* src = x + (size_t)(m0 + li) * 256 + d0 + dq;
    float4 v0 = ((const float4*)src)[0];
    float4 v1 = ((const float4*)src)[1];
    float4 v2 = ((const float4*)src)[2];
    float4 v3 = ((const float4*)src)[3];
    half8 h0, h1;
    h0[0]=(_Float16)v0.x; h0[1]=(_Float16)v0.y; h0[2]=(_Float16)v0.z; h0[3]=(_Float16)v0.w;
    h0[4]=(_Float16)v1.x; h0[5]=(_Float16)v1.y; h0[6]=(_Float16)v1.z; h0[7]=(_Float16)v1.w;
    h1[0]=(_Float16)v2.x; h1[1]=(_Float16)v2.y; h1[2]=(_Float16)v2.z; h1[3]=(_Float16)v2.w;
    h1[4]=(_Float16)v3.x; h1[5]=(_Float16)v3.y; h1[6]=(_Float16)v3.z; h1[7]=(_Float16)v3.w;
    *(half8*)&t16[li][dq] = h0;
    *(half8*)&t16[li][dq + 8] = h1;
  }
  __syncthreads();
  {
    int dj = tid >> 2, lq = (tid & 3) * 16;
    half8 o0, o1;
#pragma unroll
    for (int i = 0; i < 8; ++i) {
      o0[i] = t16[lq + i][dj];
      o1[i] = t16[lq + 8 + i][dj];
    }
    _Float16* dst = x16 + (size_t)(d0 + dj) * 65536 + m0 + lq;
    ((half8*)dst)[0] = o0;
    ((half8*)dst)[1] = o1;
  }
}

// ---------------- K_mm1: chunk-local states L = Vm @ u ------------------
// one wg per (d, dir); 256 thr = 4 waves, wave wv owns 64 cols (col=b*16+c)
// Sloc_T layout: [b][dir][c][d][n2(64)] fp32
__global__ __launch_bounds__(256) void k_mm1(
    const _Float16* __restrict__ x16, const _Float16* __restrict__ Vm,
    float* __restrict__ Sloc) {
  const int d = blockIdx.x, dir = blockIdx.y;
  const int tid = threadIdx.x, lane = tid & 63, wv = tid >> 6;
  __shared__ __align__(16) _Float16 ub[256][24];  // 16 tau + 8 pad
  floatx16 acc[2][2];
#pragma unroll
  for (int a = 0; a < 2; ++a)
#pragma unroll
    for (int b = 0; b < 2; ++b)
#pragma unroll
      for (int i = 0; i < 16; ++i) acc[a][b][i] = 0.f;

  const _Float16* vmp = Vm + (size_t)(dir * 256 + d) * 64 * 256;
  const int arow = lane & 31, ak = (lane >> 5) * 8;
  const int colb = wv * 64;

  for (int ks = 0; ks < 16; ++ks) {
    const int tau0 = ks * 16;
    __syncthreads();
    {
      int col = tid;
      int b = col >> 4, c = col & 15;
      const _Float16* up = x16 + (size_t)d * 65536 + b * 4096 + c * 256 + tau0;
      ((int4*)&ub[col][0])[0] = ((const int4*)up)[0];
      ((int4*)&ub[col][0])[1] = ((const int4*)up)[1];
    }
    __syncthreads();
    half8 a0 = *(const half8*)(vmp + (size_t)(0 * 32 + arow) * 256 + tau0 + ak);
    half8 a1 = *(const half8*)(vmp + (size_t)(1 * 32 + arow) * 256 + tau0 + ak);
    half8 b0 = *(const half8*)&ub[colb + arow][ak];
    half8 b1 = *(const half8*)&ub[colb + 32 + arow][ak];
    acc[0][0] = __builtin_amdgcn_mfma_f32_32x32x16_f16(a0, b0, acc[0][0], 0, 0, 0);
    acc[0][1] = __builtin_amdgcn_mfma_f32_32x32x16_f16(a0, b1, acc[0][1], 0, 0, 0);
    acc[1][0] = __builtin_amdgcn_mfma_f32_32x32x16_f16(a1, b0, acc[1][0], 0, 0, 0);
    acc[1][1] = __builtin_amdgcn_mfma_f32_32x32x16_f16(a1, b1, acc[1][1], 0, 0, 0);
  }
  const int hi = lane >> 5;
#pragma unroll
  for (int rt = 0; rt < 2; ++rt)
#pragma unroll
    for (int ct = 0; ct < 2; ++ct) {
      int coll = colb + ct * 32 + (lane & 31);
      int b = coll >> 4, c = coll & 15;
      float* sp = Sloc + ((((size_t)(b * 2 + dir)) * 16 + c) * 256 + d) * 64;
#pragma unroll
      for (int r = 0; r < 16; r += 2) {
        int n2 = (r & 3) + 8 * (r >> 2) + 4 * hi + rt * 32;
        float2 v;
        v.x = acc[rt][ct][r];
        v.y = acc[rt][ct][r + 1];
        *(float2*)(sp + n2) = v;
      }
    }
}

// ---------------- K_scan2: cross-chunk prefix (in-place on Sloc_T) ------
// grid (Bsz, 2, 4): d = bz*64 + tid>>2, h = tid&3 owns modes [h*8,h*8+8)
// dir0: chunks 0..15 ; dir1: chunks 15..0 (spatial chunk index both dirs)
__global__ __launch_bounds__(256) void k_scan2(
    const float* __restrict__ wtb, float* __restrict__ S) {
  const int b = blockIdx.x, dir = blockIdx.y;
  const int d = blockIdx.z * 64 + (threadIdx.x >> 2), h = threadIdx.x & 3;
  const int nbase = h * 8;
  float wTr[8], wTi[8], sr[8], si[8];
  const float* wt = wtb + (dir * 256 + d) * 64;
#pragma unroll
  for (int n = 0; n < 8; ++n) {
    wTr[n] = wt[2 * (nbase + n)];
    wTi[n] = wt[2 * (nbase + n) + 1];
    sr[n] = 0.f; si[n] = 0.f;
  }
  for (int cc = 0; cc < NCH; ++cc) {
    int c = dir ? (NCH - 1 - cc) : cc;
    float* p = S + ((((size_t)(b * 2 + dir)) * 16 + c) * 256 + d) * 64;
#pragma unroll
    for (int n = 0; n < 8; ++n) {
      int n2 = 2 * (nbase + n);
      float lr = p[n2], li = p[n2 + 1];
      p[n2] = sr[n]; p[n2 + 1] = si[n];
      float t0  = fmaf(wTr[n], sr[n], lr);
      float nsr = fmaf(-wTi[n], si[n], t0);
      float nsi = fmaf(wTr[n], si[n], li);
      nsi = fmaf(wTi[n], sr[n], nsi);
      sr[n] = nsr; si[n] = nsi;
    }
  }
}

// ---------------- K_mm2: Y = Toeplitz(K)@u + P@S + Dk*u, GELU -> ActT ---
// one wg per (d, dir); 512 thr = 8 waves; wave wv owns t rows [wv*32,+32)
// ActT layout: [ch = dir*256+d][m = b*4096 + c*256 + t] bf16
__global__ __launch_bounds__(512) void k_mm2(
    const _Float16* __restrict__ x16, const _Float16* __restrict__ KK,
    const _Float16* __restrict__ P, const float* __restrict__ Sstart,
    const float* __restrict__ Dskip, bf16* __restrict__ ActT) {
  const int d = blockIdx.x, dir = blockIdx.y;
  const int tid = threadIdx.x, lane = tid & 63, wv = tid >> 6;
  __shared__ __align__(16) _Float16 ub[64][272];   // [col][256 tau + 16 pad]
  __shared__ __align__(16) _Float16 sb[64][72];    // [col][64 n2 + 8 pad]
  __shared__ __align__(16) _Float16 kks[8][520];   // 8 shifted copies

  // stage shifted KK copies: kks[r][x] = KK[x+r] (zero-padded)
  {
    const _Float16* kg = KK + (dir * 256 + d) * 512;
#pragma unroll
    for (int rr = 0; rr < 8; ++rr)
      for (int xx = tid; xx < 520; xx += 512) {
        int s = xx + rr;
        kks[rr][xx] = (s < 512) ? kg[s] : (_Float16)0.f;
      }
  }
  const float Dk = Dskip[d];
  const int t = wv * 32 + (lane & 31);
  const int hi = lane >> 5;
  const int r_sh = (255 - t) & 7;
  const _Float16* pp = P + (size_t)(dir * 256 + d) * 256 * 64 + (size_t)t * 64;

  for (int cb = 0; cb < 4; ++cb) {
    __syncthreads();
    {  // stage u: 64 cols x 256 tau (32 halves = 4 x int4 per (col,part))
      int col = tid >> 3, part = tid & 7;
      int coll = cb * 64 + col;
      int b = coll >> 4, c = coll & 15;
      const _Float16* up = x16 + (size_t)d * 65536 + b * 4096 + c * 256 + part * 32;
      ((int4*)&ub[col][part * 32])[0] = ((const int4*)up)[0];
      ((int4*)&ub[col][part * 32])[1] = ((const int4*)up)[1];
      ((int4*)&ub[col][part * 32])[2] = ((const int4*)up)[2];
      ((int4*)&ub[col][part * 32])[3] = ((const int4*)up)[3];
    }
    {  // stage S: 64 cols x 64 n2 (fp32 -> fp16)
      int col = tid >> 3, part = tid & 7;
      int coll = cb * 64 + col;
      int b = coll >> 4, c = coll & 15;
      const float* sp = Sstart + ((((size_t)(b * 2 + dir)) * 16 + c) * 256 + d) * 64 + part * 8;
      float4 f0 = ((const float4*)sp)[0];
      float4 f1 = ((const float4*)sp)[1];
      half8 hv;
      hv[0]=(_Float16)f0.x; hv[1]=(_Float16)f0.y; hv[2]=(_Float16)f0.z; hv[3]=(_Float16)f0.w;
      hv[4]=(_Float16)f1.x; hv[5]=(_Float16)f1.y; hv[6]=(_Float16)f1.z; hv[7]=(_Float16)f1.w;
      *(half8*)&sb[col][part * 8] = hv;
    }
    __syncthreads();

    floatx16 acc0, acc1;
#pragma unroll
    for (int i = 0; i < 16; ++i) { acc0[i] = 0.f; acc1[i] = 0.f; }

    // conv: Y += Toeplitz @ u   (A[t][tau] = KK[255 - t + tau])
#pragma unroll
    for (int ks = 0; ks < 16; ++ks) {
      int i0 = 255 - t + ks * 16 + hi * 8;
      half8 af = *(const half8*)&kks[r_sh][i0 - r_sh];
      half8 b0 = *(const half8*)&ub[(lane & 31)][ks * 16 + hi * 8];
      half8 b1 = *(const half8*)&ub[32 + (lane & 31)][ks * 16 + hi * 8];
      acc0 = __builtin_amdgcn_mfma_f32_32x32x16_f16(af, b0, acc0, 0, 0, 0);
      acc1 = __builtin_amdgcn_mfma_f32_32x32x16_f16(af, b1, acc1, 0, 0, 0);
    }
    // boundary: Y += P @ S
#pragma unroll
    for (int ks = 0; ks < 4; ++ks) {
      half8 af = *(const half8*)(pp + ks * 16 + hi * 8);
      half8 b0 = *(const half8*)&sb[(lane & 31)][ks * 16 + hi * 8];
      half8 b1 = *(const half8*)&sb[32 + (lane & 31)][ks * 16 + hi * 8];
      acc0 = __builtin_amdgcn_mfma_f32_32x32x16_f16(af, b0, acc0, 0, 0, 0);
      acc1 = __builtin_amdgcn_mfma_f32_32x32x16_f16(af, b1, acc1, 0, 0, 0);
    }
    // epilogue: skip + gelu -> ActT (packed 2x bf16 per dword store)
#pragma unroll
    for (int ct = 0; ct < 2; ++ct) {
      int coll = cb * 64 + ct * 32 + (lane & 31);
      int b = coll >> 4, c = coll & 15;
      bf16* op = ActT + (size_t)(dir * 256 + d) * 65536 + b * 4096 + c * 256;
      int ucol = ct * 32 + (lane & 31);
#pragma unroll
      for (int r = 0; r < 16; r += 2) {
        int tt = (r & 3) + 8 * (r >> 2) + 4 * hi + wv * 32;
        float a0 = (ct ? acc1[r] : acc0[r]);
        float a1 = (ct ? acc1[r + 1] : acc0[r + 1]);
        float u0 = (float)ub[ucol][tt];
        float u1 = (float)ub[ucol][tt + 1];
        float g0 = gelu_tanh(fmaf(u0, Dk, a0));
        float g1 = gelu_tanh(fmaf(u1, Dk, a1));
        bf16 h0 = __float2bfloat16(g0);
        bf16 h1 = __float2bfloat16(g1);
        unsigned pk = (unsigned)*(unsigned short*)&h0 |
                      ((unsigned)*(unsigned short*)&h1 << 16);
        *(unsigned*)(op + tt) = pk;
      }
    }
  }
}

// ---------------- K_tr2: ActT[ch][m] -> Act[m][ch] (bf16) ---------------
__global__ __launch_bounds__(256) void k_tr2(
    const bf16* __restrict__ AT, bf16* __restrict__ A) {
  __shared__ __align__(16) short tl[64][72];
  const int m0 = blockIdx.x * 64, ch0 = blockIdx.y * 64;
  const int tid = threadIdx.x;
  {
    int chi = tid >> 2, mq = (tid & 3) * 16;
    const short* src = (const short*)AT + (size_t)(ch0 + chi) * 65536 + m0 + mq;
    *(int4*)&tl[chi][mq] = ((const int4*)src)[0];
    *(int4*)&tl[chi][mq + 8] = ((const int4*)src)[1];
  }
  __syncthreads();
  {
    int mi = tid >> 2, chq = (tid & 3) * 16;
    short8 s0, s1;
#pragma unroll
    for (int i = 0; i < 8; ++i) {
      s0[i] = tl[chq + i][mi];
      s1[i] = tl[chq + 8 + i][mi];
    }
    short* dst = (short*)A + (size_t)(m0 + mi) * 512 + ch0 + chq;
    ((short8*)dst)[0] = s0;
    ((short8*)dst)[1] = s1;
  }
}

// ---------------- K4: GEMM (M,K=512)x(1024,K) + bias + GLU -> z ---------
// v2: 128M x 64N(a)+64N(g) tile -> acc 64 regs (unified-RF!), 3 waves/SIMD.
// Round-6 bug: 128x128 tile => 128 acc regs + 148 arch = 276/wave = 1
// wave/SIMD (Occupancy 11.7% == 4 waves/CU), MfmaUtil 11.8%.
// grid (nj=8 fastest, bi=512): 8 adjacent blocks share one Act M-tile.
// T14: next-tile global loads issued before the MFMA cluster, LDS-written
// after the 2nd barrier.
#define LDK 40
__global__ __launch_bounds__(256, 3) void k_gemm(
    const bf16* __restrict__ Act, const bf16* __restrict__ W,
    const float* __restrict__ bias, float* __restrict__ z) {
  __shared__ __align__(16) short As[128 * LDK];
  __shared__ __align__(16) short Bas[64 * LDK];
  __shared__ __align__(16) short Bgs[64 * LDK];
  const int nj = blockIdx.x, bi = blockIdx.y;
  const int tid = threadIdx.x, lane = tid & 63, wv = tid >> 6;
  const int wm = (wv & 1) * 64, wn = (wv >> 1) * 32;
  const int M0 = bi * 128, N0 = nj * 64;
  floatx4 acc_a[4][2], acc_g[4][2];
#pragma unroll
  for (int i = 0; i < 4; ++i)
#pragma unroll
    for (int j = 0; j < 2; ++j) {
      acc_a[i][j] = (floatx4){0.f, 0.f, 0.f, 0.f};
      acc_g[i][j] = (floatx4){0.f, 0.f, 0.f, 0.f};
    }
  const int row2 = tid >> 2;        // 0..63
  const int kc = (tid & 3) * 8;     // 0,8,16,24 elements
  const int fr = lane & 15, fk = (lane >> 4) * 8;

  const bf16* pa0 = Act + (size_t)(M0 + row2) * 512 + kc;
  const bf16* pa1 = Act + (size_t)(M0 + row2 + 64) * 512 + kc;
  const bf16* pba = W + (size_t)(N0 + row2) * 512 + kc;
  const bf16* pbg = W + (size_t)(512 + N0 + row2) * 512 + kc;

  // prologue: stage k-tile 0
  *(int4*)&As[row2 * LDK + kc]        = *(const int4*)pa0;
  *(int4*)&As[(row2 + 64) * LDK + kc] = *(const int4*)pa1;
  *(int4*)&Bas[row2 * LDK + kc]       = *(const int4*)pba;
  *(int4*)&Bgs[row2 * LDK + kc]       = *(const int4*)pbg;

  for (int kb = 0; kb < 512; kb += 32) {
    __syncthreads();   // staged tile visible
    short8 af[4], bfa[2], bfg[2];
#pragma unroll
    for (int i = 0; i < 4; ++i) af[i]  = *(const short8*)&As[(wm + 16 * i + fr) * LDK + fk];
#pragma unroll
    for (int j = 0; j < 2; ++j) bfa[j] = *(const short8*)&Bas[(wn + 16 * j + fr) * LDK + fk];
#pragma unroll
    for (int j = 0; j < 2; ++j) bfg[j] = *(const short8*)&Bgs[(wn + 16 * j + fr) * LDK + fk];
    // issue next-tile global loads now; they land during the MFMA cluster
    int4 ga0, ga1, gb, gg;
    const bool more = (kb + 32) < 512;
    if (more) {
      ga0 = *(const int4*)(pa0 + kb + 32);
      ga1 = *(const int4*)(pa1 + kb + 32);
      gb  = *(const int4*)(pba + kb + 32);
      gg  = *(const int4*)(pbg + kb + 32);
    }
#pragma unroll
    for (int i = 0; i < 4; ++i)
#pragma unroll
      for (int j = 0; j < 2; ++j) {
        acc_a[i][j] = __builtin_amdgcn_mfma_f32_16x16x32_bf16(af[i], bfa[j], acc_a[i][j], 0, 0, 0);
        acc_g[i][j] = __builtin_amdgcn_mfma_f32_16x16x32_bf16(af[i], bfg[j], acc_g[i][j], 0, 0, 0);
      }
    __syncthreads();   // all reads of this tile done
    if (more) {
      *(int4*)&As[row2 * LDK + kc]        = ga0;
      *(int4*)&As[(row2 + 64) * LDK + kc] = ga1;
      *(int4*)&Bas[row2 * LDK + kc]       = gb;
      *(int4*)&Bgs[row2 * LDK + kc]       = gg;
    }
  }
  // epilogue: bias + GLU, write z[m][o] fp32, o in [N0, N0+64)
  const int col = lane & 15, rquad = (lane >> 4) * 4;
#pragma unroll
  for (int j = 0; j < 2; ++j) {
    int o = N0 + wn + 16 * j + col;
    float ba = bias[o];
    float bg = bias[512 + o];
#pragma unroll
    for (int i = 0; i < 4; ++i) {
      int mbase = M0 + wm + 16 * i + rquad;
#pragma unroll
      for (int rg = 0; rg < 4; ++rg) {
        float a = acc_a[i][j][rg] + ba;
        float g = acc_g[i][j][rg] + bg;
        float zv = a * __frcp_rn(1.f + __expf(-g));
        z[(size_t)(mbase + rg) * 512 + o] = zv;
      }
    }
  }
}

// ---------------- K5: LayerNorm over 512 (in-place on d_out) ------------
__global__ __launch_bounds__(256) void k_ln(
    float* __restrict__ z, const float* __restrict__ gamma,
    const float* __restrict__ beta) {
  const int m = blockIdx.x * 4 + (threadIdx.x >> 6);
  const int lane = threadIdx.x & 63;
  float* zp = z + (size_t)m * 512;
  float v[8], s = 0.f, sq = 0.f;
#pragma unroll
  for (int j = 0; j < 8; ++j) {
    v[j] = zp[j * 64 + lane];
    s += v[j];
    sq = fmaf(v[j], v[j], sq);
  }
#pragma unroll
  for (int off = 32; off > 0; off >>= 1) {
    s += __shfl_xor(s, off);
    sq += __shfl_xor(sq, off);
  }
  float mean = s * (1.f / 512.f);
  float var = fmaf(-mean, mean, sq * (1.f / 512.f));
  float inv = rsqrtf(var + 1e-5f);
#pragma unroll
  for (int j = 0; j < 8; ++j) {
    int cidx = j * 64 + lane;
    float g = gamma[cidx], be = beta[cidx];
    zp[cidx] = fmaf((v[j] - mean) * inv, g, be);
  }
}

extern "C" void kernel_launch(void* const* d_in, const int* in_sizes, int n_in,
                              void* d_out, int out_size, void* d_ws, size_t ws_size,
                              hipStream_t stream) {
  const float* x      = (const float*)d_in[0];
  const float* ldt_fw = (const float*)d_in[1];
  const float* lar_fw = (const float*)d_in[2];
  const float* ai_fw  = (const float*)d_in[3];
  const float* C_fw   = (const float*)d_in[4];
  const float* ldt_bw = (const float*)d_in[5];
  const float* lar_bw = (const float*)d_in[6];
  const float* ai_bw  = (const float*)d_in[7];
  const float* C_bw   = (const float*)d_in[8];
  const float* Dskip  = (const float*)d_in[9];
  const float* W      = (const float*)d_in[10];
  const float* bias   = (const float*)d_in[11];
  const float* gamma  = (const float*)d_in[12];
  const float* beta   = (const float*)d_in[13];
  float* out = (float*)d_out;

  // workspace map (bytes):
  //  [0)          ActT   512*65536*2  = 67,108,864
  //  [67108864)   SlocT  16*2*16*256*64*4 = 33,554,432
  //  [100663296)  x16    256*65536*2  = 33,554,432
  //  [134217728)  Vm     2*256*64*256*2 = 16,777,216
  //  [150994944)  P      2*256*256*64*2 = 16,777,216
  //  [167772160)  KK     2*256*512*2  = 524,288
  //  [168296448)  wtb    2*256*64*4   = 131,072
  //  [168427520)  Wb     1,048,576     -> total ~169.5 MB
  //  Act (final [m][ch], 67,108,864 B) aliases [SlocT + x16]; both dead by k_tr2.
  char* wsb = (char*)d_ws;
  bf16*     ActT  = (bf16*)wsb;
  float*    SlocT = (float*)(wsb + 67108864u);
  _Float16* x16   = (_Float16*)(wsb + 100663296u);
  _Float16* Vm    = (_Float16*)(wsb + 134217728u);
  _Float16* P     = (_Float16*)(wsb + 150994944u);
  _Float16* KK    = (_Float16*)(wsb + 167772160u);
  float*    wtb   = (float*)(wsb + 168296448u);
  bf16*     Wb    = (bf16*)(wsb + 168427520u);
  bf16*     Act   = (bf16*)(wsb + 67108864u);   // alias over SlocT+x16

  k_prep<<<dim3(256, 2), dim3(64), 0, stream>>>(
      ldt_fw, lar_fw, ai_fw, C_fw, ldt_bw, lar_bw, ai_bw, C_bw, Vm, P, KK, wtb);
  k_wconv<<<dim3(2048), dim3(256), 0, stream>>>(W, Wb, 1024 * 512);
  k_tr<<<dim3(Mtot / 64, 4), dim3(256), 0, stream>>>(x, x16);
  k_mm1<<<dim3(256, 2), dim3(256), 0, stream>>>(x16, Vm, SlocT);
  k_scan2<<<dim3(Bsz, 2, 4), dim3(256), 0, stream>>>(wtb, SlocT);
  k_mm2<<<dim3(256, 2), dim3(512), 0, stream>>>(x16, KK, P, SlocT, Dskip, ActT);
  k_tr2<<<dim3(Mtot / 64, 8), dim3(256), 0, stream>>>(ActT, Act);
  k_gemm<<<dim3(8, Mtot / 128), dim3(256), 0, stream>>>(Act, Wb, bias, out);
  k_ln<<<dim3(Mtot / 4), dim3(256), 0, stream>>>(out, gamma, beta);
}

// Round 8
// 516.076 us; speedup vs baseline: 1.9189x; 1.0309x over previous
//
#include <hip/hip_runtime.h>
#include <hip/hip_bf16.h>
#include <cstdint>
#include <cstddef>

typedef __hip_bfloat16 bf16;
typedef __attribute__((ext_vector_type(8))) short short8;
typedef __attribute__((ext_vector_type(4))) float floatx4;
typedef __attribute__((ext_vector_type(16))) float floatx16;
typedef __attribute__((ext_vector_type(8))) _Float16 half8;

#define Bsz 16
#define Lseq 4096
#define Hd 256
#define NM 32          // complex modes per channel
#define NCH 16         // chunks
#define TCH 256        // chunk length (NCH*TCH == Lseq)
#define Mtot (Bsz*Lseq)

__device__ __forceinline__ float gelu_tanh(float y) {
  float y2 = y * y;
  float q = fmaf(0.044715f, y2, 1.0f);
  float a = 1.5957691216057308f * y * q;
  float e = __expf(-a);
  return y * __frcp_rn(1.0f + e);
}

// ---------------- K_prep: per-(dir,d) tables for the matmul formulation ---
// KK[dir][d][512]  fp16: dir0: KK[i]=K[255-i] (i<=255) else 0  (A[t][tau]=KK[255-t+tau])
//                        dir1: KK[i]=K[i-255] (i>=255) else 0
// Vm[dir][d][n2][256] fp16: dir0: Vm[2n][tau]=Re(w^{255-tau}) ; dir1: Re(w^{tau})
// P [dir][d][256][64] fp16: dir0: P[t][2n]=Re(C w^{t+1}), [2n+1]=-Im(C w^{t+1})
//                           dir1: exponent 256-t
// wtb[dir][d][64] fp32: [2n]=Re(w^256), [2n+1]=Im(w^256)
__global__ __launch_bounds__(64) void k_prep(
    const float* __restrict__ ldt_fw, const float* __restrict__ lar_fw,
    const float* __restrict__ ai_fw,  const float* __restrict__ C_fw,
    const float* __restrict__ ldt_bw, const float* __restrict__ lar_bw,
    const float* __restrict__ ai_bw,  const float* __restrict__ C_bw,
    _Float16* __restrict__ Vm, _Float16* __restrict__ P,
    _Float16* __restrict__ KK, float* __restrict__ wtb) {
  const int d = blockIdx.x, dir = blockIdx.y;
  const int lane = threadIdx.x;
  const int n = lane & 31;
  const bool active = lane < 32;
  const float* ldt = dir ? ldt_bw : ldt_fw;
  const float* lar = dir ? lar_bw : lar_fw;
  const float* ai  = dir ? ai_bw  : ai_fw;
  const float* C   = dir ? C_bw   : C_fw;

  float dt = expf(ldt[d]);
  float Ar = -expf(lar[d * NM + n]);
  float Ai = ai[d * NM + n];
  float c0 = C[(d * NM + n) * 2 + 0];
  float c1 = C[(d * NM + n) * 2 + 1];

  float er = expf(Ar * dt);
  float sn, cs;
  sincosf(Ai * dt, &sn, &cs);
  float wr = er * cs, wi = er * sn;
  // Ceff = 2*Cc*(w-1)/(A+1e-8)
  float nr = wr - 1.f, ni = wi;
  float tr_ = c0 * nr - c1 * ni;
  float ti  = c0 * ni + c1 * nr;
  float dr = Ar + 1e-8f, di = Ai;
  float inv = 1.f / (dr * dr + di * di);
  float Cr = 2.f * (tr_ * dr + ti * di) * inv;
  float Ci = 2.f * (ti * dr - tr_ * di) * inv;
  // wT = w^256 (direct exp for accuracy)
  float erT = expf(256.f * Ar * dt);
  float snT, csT;
  sincosf(256.f * Ai * dt, &snT, &csT);
  if (active) {
    wtb[(dir * 256 + d) * 64 + 2 * n]     = erT * csT;
    wtb[(dir * 256 + d) * 64 + 2 * n + 1] = erT * snT;
  }
  // zero KK
  _Float16* kk = KK + (dir * 256 + d) * 512;
  for (int i = lane; i < 512; i += 64) kk[i] = (_Float16)0.f;
  __syncthreads();

  _Float16* vm = Vm + (size_t)(dir * 256 + d) * 64 * 256;
  _Float16* pp = P  + (size_t)(dir * 256 + d) * 256 * 64;
  float pr = 1.f, pi = 0.f;  // w^j
  for (int j = 0; j <= 256; ++j) {
    float kc = active ? (Cr * pr - Ci * pi) : 0.f;
#pragma unroll
    for (int off = 32; off > 0; off >>= 1) kc += __shfl_xor(kc, off);
    if (lane == 0 && j <= 255) {
      int i = dir ? (255 + j) : (255 - j);
      kk[i] = (_Float16)kc;
    }
    if (active) {
      if (j <= 255) {
        int tv = dir ? j : (255 - j);
        vm[(2 * n) * 256 + tv]     = (_Float16)pr;
        vm[(2 * n + 1) * 256 + tv] = (_Float16)pi;
      }
      if (j >= 1) {
        int t = dir ? (256 - j) : (j - 1);
        float cwr = Cr * pr - Ci * pi;
        float cwi = Cr * pi + Ci * pr;
        pp[t * 64 + 2 * n]     = (_Float16)cwr;
        pp[t * 64 + 2 * n + 1] = (_Float16)(-cwi);
      }
    }
    float npr = pr * wr - pi * wi;
    float npi = pr * wi + pi * wr;
    pr = npr; pi = npi;
  }
}

// ---------------- K0b: conv_w fp32 -> bf16 ----------------
__global__ __launch_bounds__(256) void k_wconv(
    const float* __restrict__ W, bf16* __restrict__ Wb, int n) {
  int i = blockIdx.x * 256 + threadIdx.x;
  if (i < n) Wb[i] = __float2bfloat16(W[i]);
}

// ---------------- K_tr: x[m=b*L+l][d] fp32 -> x16[d][m] fp16 ------------
__global__ __launch_bounds__(256) void k_tr(
    const float* __restrict__ x, _Float16* __restrict__ x16) {
  __shared__ __align__(16) _Float16 t16[64][72];
  const int m0 = blockIdx.x * 64, d0 = blockIdx.y * 64;
  const int tid = threadIdx.x;
  {
    int li = tid >> 2, dq = (tid & 3) * 16;
    const float* src = x + (size_t)(m0 + li) * 256 + d0 + dq;
    float4 v0 = ((const float4*)src)[0];
    float4 v1 = ((const float4*)src)[1];
    float4 v2 = ((const float4*)src)[2];
    float4 v3 = ((const float4*)src)[3];
    half8 h0, h1;
    h0[0]=(_Float16)v0.x; h0[1]=(_Float16)v0.y; h0[2]=(_Float16)v0.z; h0[3]=(_Float16)v0.w;
    h0[4]=(_Float16)v1.x; h0[5]=(_Float16)v1.y; h0[6]=(_Float16)v1.z; h0[7]=(_Float16)v1.w;
    h1[0]=(_Float16)v2.x; h1[1]=(_Float16)v2.y; h1[2]=(_Float16)v2.z; h1[3]=(_Float16)v2.w;
    h1[4]=(_Float16)v3.x; h1[5]=(_Float16)v3.y; h1[6]=(_Float16)v3.z; h1[7]=(_Float16)v3.w;
    *(half8*)&t16[li][dq] = h0;
    *(half8*)&t16[li][dq + 8] = h1;
  }
  __syncthreads();
  {
    int dj = tid >> 2, lq = (tid & 3) * 16;
    half8 o0, o1;
#pragma unroll
    for (int i = 0; i < 8; ++i) {
      o0[i] = t16[lq + i][dj];
      o1[i] = t16[lq + 8 + i][dj];
    }
    _Float16* dst = x16 + (size_t)(d0 + dj) * 65536 + m0 + lq;
    ((half8*)dst)[0] = o0;
    ((half8*)dst)[1] = o1;
  }
}

// ---------------- K_mm1: chunk-local states L = Vm @ u ------------------
// one wg per (d, dir); 256 thr = 4 waves, wave wv owns 64 cols (col=b*16+c)
// Sloc_T layout: [b][dir][c][d][n2(64)] fp32
__global__ __launch_bounds__(256) void k_mm1(
    const _Float16* __restrict__ x16, const _Float16* __restrict__ Vm,
    float* __restrict__ Sloc) {
  const int d = blockIdx.x, dir = blockIdx.y;
  const int tid = threadIdx.x, lane = tid & 63, wv = tid >> 6;
  __shared__ __align__(16) _Float16 ub[256][24];  // 16 tau + 8 pad
  floatx16 acc[2][2];
#pragma unroll
  for (int a = 0; a < 2; ++a)
#pragma unroll
    for (int b = 0; b < 2; ++b)
#pragma unroll
      for (int i = 0; i < 16; ++i) acc[a][b][i] = 0.f;

  const _Float16* vmp = Vm + (size_t)(dir * 256 + d) * 64 * 256;
  const int arow = lane & 31, ak = (lane >> 5) * 8;
  const int colb = wv * 64;

  for (int ks = 0; ks < 16; ++ks) {
    const int tau0 = ks * 16;
    __syncthreads();
    {
      int col = tid;
      int b = col >> 4, c = col & 15;
      const _Float16* up = x16 + (size_t)d * 65536 + b * 4096 + c * 256 + tau0;
      ((int4*)&ub[col][0])[0] = ((const int4*)up)[0];
      ((int4*)&ub[col][0])[1] = ((const int4*)up)[1];
    }
    __syncthreads();
    half8 a0 = *(const half8*)(vmp + (size_t)(0 * 32 + arow) * 256 + tau0 + ak);
    half8 a1 = *(const half8*)(vmp + (size_t)(1 * 32 + arow) * 256 + tau0 + ak);
    half8 b0 = *(const half8*)&ub[colb + arow][ak];
    half8 b1 = *(const half8*)&ub[colb + 32 + arow][ak];
    acc[0][0] = __builtin_amdgcn_mfma_f32_32x32x16_f16(a0, b0, acc[0][0], 0, 0, 0);
    acc[0][1] = __builtin_amdgcn_mfma_f32_32x32x16_f16(a0, b1, acc[0][1], 0, 0, 0);
    acc[1][0] = __builtin_amdgcn_mfma_f32_32x32x16_f16(a1, b0, acc[1][0], 0, 0, 0);
    acc[1][1] = __builtin_amdgcn_mfma_f32_32x32x16_f16(a1, b1, acc[1][1], 0, 0, 0);
  }
  const int hi = lane >> 5;
#pragma unroll
  for (int rt = 0; rt < 2; ++rt)
#pragma unroll
    for (int ct = 0; ct < 2; ++ct) {
      int coll = colb + ct * 32 + (lane & 31);
      int b = coll >> 4, c = coll & 15;
      float* sp = Sloc + ((((size_t)(b * 2 + dir)) * 16 + c) * 256 + d) * 64;
#pragma unroll
      for (int r = 0; r < 16; r += 2) {
        int n2 = (r & 3) + 8 * (r >> 2) + 4 * hi + rt * 32;
        float2 v;
        v.x = acc[rt][ct][r];
        v.y = acc[rt][ct][r + 1];
        *(float2*)(sp + n2) = v;
      }
    }
}

// ---------------- K_scan2: cross-chunk prefix (in-place on Sloc_T) ------
// grid (Bsz, 2, 4): d = bz*64 + tid>>2, h = tid&3 owns modes [h*8,h*8+8)
// dir0: chunks 0..15 ; dir1: chunks 15..0 (spatial chunk index both dirs)
__global__ __launch_bounds__(256) void k_scan2(
    const float* __restrict__ wtb, float* __restrict__ S) {
  const int b = blockIdx.x, dir = blockIdx.y;
  const int d = blockIdx.z * 64 + (threadIdx.x >> 2), h = threadIdx.x & 3;
  const int nbase = h * 8;
  float wTr[8], wTi[8], sr[8], si[8];
  const float* wt = wtb + (dir * 256 + d) * 64;
#pragma unroll
  for (int n = 0; n < 8; ++n) {
    wTr[n] = wt[2 * (nbase + n)];
    wTi[n] = wt[2 * (nbase + n) + 1];
    sr[n] = 0.f; si[n] = 0.f;
  }
  for (int cc = 0; cc < NCH; ++cc) {
    int c = dir ? (NCH - 1 - cc) : cc;
    float* p = S + ((((size_t)(b * 2 + dir)) * 16 + c) * 256 + d) * 64;
#pragma unroll
    for (int n = 0; n < 8; ++n) {
      int n2 = 2 * (nbase + n);
      float lr = p[n2], li = p[n2 + 1];
      p[n2] = sr[n]; p[n2 + 1] = si[n];
      float t0  = fmaf(wTr[n], sr[n], lr);
      float nsr = fmaf(-wTi[n], si[n], t0);
      float nsi = fmaf(wTr[n], si[n], li);
      nsi = fmaf(wTi[n], sr[n], nsi);
      sr[n] = nsr; si[n] = nsi;
    }
  }
}

// ---------------- K_mm2: Y = Toeplitz(K)@u + P@S + Dk*u, GELU -> ActT ---
// one wg per (d, dir); 512 thr = 8 waves; wave wv owns t rows [wv*32,+32)
// ActT layout: [ch = dir*256+d][m = b*4096 + c*256 + t] bf16
__global__ __launch_bounds__(512) void k_mm2(
    const _Float16* __restrict__ x16, const _Float16* __restrict__ KK,
    const _Float16* __restrict__ P, const float* __restrict__ Sstart,
    const float* __restrict__ Dskip, bf16* __restrict__ ActT) {
  const int d = blockIdx.x, dir = blockIdx.y;
  const int tid = threadIdx.x, lane = tid & 63, wv = tid >> 6;
  __shared__ __align__(16) _Float16 ub[64][272];   // [col][256 tau + 16 pad]
  __shared__ __align__(16) _Float16 sb[64][72];    // [col][64 n2 + 8 pad]
  __shared__ __align__(16) _Float16 kks[8][520];   // 8 shifted copies

  // stage shifted KK copies: kks[r][x] = KK[x+r] (zero-padded)
  {
    const _Float16* kg = KK + (dir * 256 + d) * 512;
#pragma unroll
    for (int rr = 0; rr < 8; ++rr)
      for (int xx = tid; xx < 520; xx += 512) {
        int s = xx + rr;
        kks[rr][xx] = (s < 512) ? kg[s] : (_Float16)0.f;
      }
  }
  const float Dk = Dskip[d];
  const int t = wv * 32 + (lane & 31);
  const int hi = lane >> 5;
  const int r_sh = (255 - t) & 7;
  const _Float16* pp = P + (size_t)(dir * 256 + d) * 256 * 64 + (size_t)t * 64;

  for (int cb = 0; cb < 4; ++cb) {
    __syncthreads();
    {  // stage u: 64 cols x 256 tau (32 halves = 4 x int4 per (col,part))
      int col = tid >> 3, part = tid & 7;
      int coll = cb * 64 + col;
      int b = coll >> 4, c = coll & 15;
      const _Float16* up = x16 + (size_t)d * 65536 + b * 4096 + c * 256 + part * 32;
      ((int4*)&ub[col][part * 32])[0] = ((const int4*)up)[0];
      ((int4*)&ub[col][part * 32])[1] = ((const int4*)up)[1];
      ((int4*)&ub[col][part * 32])[2] = ((const int4*)up)[2];
      ((int4*)&ub[col][part * 32])[3] = ((const int4*)up)[3];
    }
    {  // stage S: 64 cols x 64 n2 (fp32 -> fp16)
      int col = tid >> 3, part = tid & 7;
      int coll = cb * 64 + col;
      int b = coll >> 4, c = coll & 15;
      const float* sp = Sstart + ((((size_t)(b * 2 + dir)) * 16 + c) * 256 + d) * 64 + part * 8;
      float4 f0 = ((const float4*)sp)[0];
      float4 f1 = ((const float4*)sp)[1];
      half8 hv;
      hv[0]=(_Float16)f0.x; hv[1]=(_Float16)f0.y; hv[2]=(_Float16)f0.z; hv[3]=(_Float16)f0.w;
      hv[4]=(_Float16)f1.x; hv[5]=(_Float16)f1.y; hv[6]=(_Float16)f1.z; hv[7]=(_Float16)f1.w;
      *(half8*)&sb[col][part * 8] = hv;
    }
    __syncthreads();

    floatx16 acc0, acc1;
#pragma unroll
    for (int i = 0; i < 16; ++i) { acc0[i] = 0.f; acc1[i] = 0.f; }

    // conv: Y += Toeplitz @ u   (A[t][tau] = KK[255 - t + tau])
#pragma unroll
    for (int ks = 0; ks < 16; ++ks) {
      int i0 = 255 - t + ks * 16 + hi * 8;
      half8 af = *(const half8*)&kks[r_sh][i0 - r_sh];
      half8 b0 = *(const half8*)&ub[(lane & 31)][ks * 16 + hi * 8];
      half8 b1 = *(const half8*)&ub[32 + (lane & 31)][ks * 16 + hi * 8];
      acc0 = __builtin_amdgcn_mfma_f32_32x32x16_f16(af, b0, acc0, 0, 0, 0);
      acc1 = __builtin_amdgcn_mfma_f32_32x32x16_f16(af, b1, acc1, 0, 0, 0);
    }
    // boundary: Y += P @ S
#pragma unroll
    for (int ks = 0; ks < 4; ++ks) {
      half8 af = *(const half8*)(pp + ks * 16 + hi * 8);
      half8 b0 = *(const half8*)&sb[(lane & 31)][ks * 16 + hi * 8];
      half8 b1 = *(const half8*)&sb[32 + (lane & 31)][ks * 16 + hi * 8];
      acc0 = __builtin_amdgcn_mfma_f32_32x32x16_f16(af, b0, acc0, 0, 0, 0);
      acc1 = __builtin_amdgcn_mfma_f32_32x32x16_f16(af, b1, acc1, 0, 0, 0);
    }
    // epilogue: skip + gelu -> ActT (packed 2x bf16 per dword store)
#pragma unroll
    for (int ct = 0; ct < 2; ++ct) {
      int coll = cb * 64 + ct * 32 + (lane & 31);
      int b = coll >> 4, c = coll & 15;
      bf16* op = ActT + (size_t)(dir * 256 + d) * 65536 + b * 4096 + c * 256;
      int ucol = ct * 32 + (lane & 31);
#pragma unroll
      for (int r = 0; r < 16; r += 2) {
        int tt = (r & 3) + 8 * (r >> 2) + 4 * hi + wv * 32;
        float a0 = (ct ? acc1[r] : acc0[r]);
        float a1 = (ct ? acc1[r + 1] : acc0[r + 1]);
        float u0 = (float)ub[ucol][tt];
        float u1 = (float)ub[ucol][tt + 1];
        float g0 = gelu_tanh(fmaf(u0, Dk, a0));
        float g1 = gelu_tanh(fmaf(u1, Dk, a1));
        bf16 h0 = __float2bfloat16(g0);
        bf16 h1 = __float2bfloat16(g1);
        unsigned pk = (unsigned)*(unsigned short*)&h0 |
                      ((unsigned)*(unsigned short*)&h1 << 16);
        *(unsigned*)(op + tt) = pk;
      }
    }
  }
}

// ---------------- K_tr2: ActT[ch][m] -> Act[m][ch] (bf16) ---------------
__global__ __launch_bounds__(256) void k_tr2(
    const bf16* __restrict__ AT, bf16* __restrict__ A) {
  __shared__ __align__(16) short tl[64][72];
  const int m0 = blockIdx.x * 64, ch0 = blockIdx.y * 64;
  const int tid = threadIdx.x;
  {
    int chi = tid >> 2, mq = (tid & 3) * 16;
    const short* src = (const short*)AT + (size_t)(ch0 + chi) * 65536 + m0 + mq;
    *(int4*)&tl[chi][mq] = ((const int4*)src)[0];
    *(int4*)&tl[chi][mq + 8] = ((const int4*)src)[1];
  }
  __syncthreads();
  {
    int mi = tid >> 2, chq = (tid & 3) * 16;
    short8 s0, s1;
#pragma unroll
    for (int i = 0; i < 8; ++i) {
      s0[i] = tl[chq + i][mi];
      s1[i] = tl[chq + 8 + i][mi];
    }
    short* dst = (short*)A + (size_t)(m0 + mi) * 512 + ch0 + chq;
    ((short8*)dst)[0] = s0;
    ((short8*)dst)[1] = s1;
  }
}

// ---------------- K4: GEMM (M,K=512)x(1024,K) + bias + GLU -> z ---------
// v3: XCD-aware swizzle. 1D grid 4096: id = g*64 + j*8 + x ->
// bi = g*8 + x, nj = j. All 8 nj-blocks sharing Act tile bi have
// id%8 == x -> same XCD (round-robin id->XCD), within a 64-id window ->
// co-resident. Round-7 bug: nj-fastest put the 8 sharers on 8 DIFFERENT
// XCD L2s -> Act fetched 8x (FETCH 264MB == 8*32+W).
// launch_bounds(256,4): budget 128 >= demand 120 (56 arch + 64 acc).
#define LDK 40
__global__ __launch_bounds__(256, 4) void k_gemm(
    const bf16* __restrict__ Act, const bf16* __restrict__ W,
    const float* __restrict__ bias, float* __restrict__ z) {
  __shared__ __align__(16) short As[128 * LDK];
  __shared__ __align__(16) short Bas[64 * LDK];
  __shared__ __align__(16) short Bgs[64 * LDK];
  const int id = blockIdx.x;
  const int x = id & 7, nj = (id >> 3) & 7, g = id >> 6;
  const int bi = g * 8 + x;
  const int tid = threadIdx.x, lane = tid & 63, wv = tid >> 6;
  const int wm = (wv & 1) * 64, wn = (wv >> 1) * 32;
  const int M0 = bi * 128, N0 = nj * 64;
  floatx4 acc_a[4][2], acc_g[4][2];
#pragma unroll
  for (int i = 0; i < 4; ++i)
#pragma unroll
    for (int j = 0; j < 2; ++j) {
      acc_a[i][j] = (floatx4){0.f, 0.f, 0.f, 0.f};
      acc_g[i][j] = (floatx4){0.f, 0.f, 0.f, 0.f};
    }
  const int row2 = tid >> 2;        // 0..63
  const int kc = (tid & 3) * 8;     // 0,8,16,24 elements
  const int fr = lane & 15, fk = (lane >> 4) * 8;

  const bf16* pa0 = Act + (size_t)(M0 + row2) * 512 + kc;
  const bf16* pa1 = Act + (size_t)(M0 + row2 + 64) * 512 + kc;
  const bf16* pba = W + (size_t)(N0 + row2) * 512 + kc;
  const bf16* pbg = W + (size_t)(512 + N0 + row2) * 512 + kc;

  // prologue: stage k-tile 0
  *(int4*)&As[row2 * LDK + kc]        = *(const int4*)pa0;
  *(int4*)&As[(row2 + 64) * LDK + kc] = *(const int4*)pa1;
  *(int4*)&Bas[row2 * LDK + kc]       = *(const int4*)pba;
  *(int4*)&Bgs[row2 * LDK + kc]       = *(const int4*)pbg;

  for (int kb = 0; kb < 512; kb += 32) {
    __syncthreads();   // staged tile visible
    short8 af[4], bfa[2], bfg[2];
#pragma unroll
    for (int i = 0; i < 4; ++i) af[i]  = *(const short8*)&As[(wm + 16 * i + fr) * LDK + fk];
#pragma unroll
    for (int j = 0; j < 2; ++j) bfa[j] = *(const short8*)&Bas[(wn + 16 * j + fr) * LDK + fk];
#pragma unroll
    for (int j = 0; j < 2; ++j) bfg[j] = *(const short8*)&Bgs[(wn + 16 * j + fr) * LDK + fk];
    // issue next-tile global loads now; they land during the MFMA cluster
    int4 ga0, ga1, gb, gg;
    const bool more = (kb + 32) < 512;
    if (more) {
      ga0 = *(const int4*)(pa0 + kb + 32);
      ga1 = *(const int4*)(pa1 + kb + 32);
      gb  = *(const int4*)(pba + kb + 32);
      gg  = *(const int4*)(pbg + kb + 32);
    }
#pragma unroll
    for (int i = 0; i < 4; ++i)
#pragma unroll
      for (int j = 0; j < 2; ++j) {
        acc_a[i][j] = __builtin_amdgcn_mfma_f32_16x16x32_bf16(af[i], bfa[j], acc_a[i][j], 0, 0, 0);
        acc_g[i][j] = __builtin_amdgcn_mfma_f32_16x16x32_bf16(af[i], bfg[j], acc_g[i][j], 0, 0, 0);
      }
    __syncthreads();   // all reads of this tile done
    if (more) {
      *(int4*)&As[row2 * LDK + kc]        = ga0;
      *(int4*)&As[(row2 + 64) * LDK + kc] = ga1;
      *(int4*)&Bas[row2 * LDK + kc]       = gb;
      *(int4*)&Bgs[row2 * LDK + kc]       = gg;
    }
  }
  // epilogue: bias + GLU, write z[m][o] fp32, o in [N0, N0+64)
  const int col = lane & 15, rquad = (lane >> 4) * 4;
#pragma unroll
  for (int j = 0; j < 2; ++j) {
    int o = N0 + wn + 16 * j + col;
    float ba = bias[o];
    float bg = bias[512 + o];
#pragma unroll
    for (int i = 0; i < 4; ++i) {
      int mbase = M0 + wm + 16 * i + rquad;
#pragma unroll
      for (int rg = 0; rg < 4; ++rg) {
        float a = acc_a[i][j][rg] + ba;
        float g = acc_g[i][j][rg] + bg;
        float zv = a * __frcp_rn(1.f + __expf(-g));
        z[(size_t)(mbase + rg) * 512 + o] = zv;
      }
    }
  }
}

// ---------------- K5: LayerNorm over 512 (in-place on d_out) ------------
__global__ __launch_bounds__(256) void k_ln(
    float* __restrict__ z, const float* __restrict__ gamma,
    const float* __restrict__ beta) {
  const int m = blockIdx.x * 4 + (threadIdx.x >> 6);
  const int lane = threadIdx.x & 63;
  float* zp = z + (size_t)m * 512;
  float v[8], s = 0.f, sq = 0.f;
#pragma unroll
  for (int j = 0; j < 8; ++j) {
    v[j] = zp[j * 64 + lane];
    s += v[j];
    sq = fmaf(v[j], v[j], sq);
  }
#pragma unroll
  for (int off = 32; off > 0; off >>= 1) {
    s += __shfl_xor(s, off);
    sq += __shfl_xor(sq, off);
  }
  float mean = s * (1.f / 512.f);
  float var = fmaf(-mean, mean, sq * (1.f / 512.f));
  float inv = rsqrtf(var + 1e-5f);
#pragma unroll
  for (int j = 0; j < 8; ++j) {
    int cidx = j * 64 + lane;
    float g = gamma[cidx], be = beta[cidx];
    zp[cidx] = fmaf((v[j] - mean) * inv, g, be);
  }
}

extern "C" void kernel_launch(void* const* d_in, const int* in_sizes, int n_in,
                              void* d_out, int out_size, void* d_ws, size_t ws_size,
                              hipStream_t stream) {
  const float* x      = (const float*)d_in[0];
  const float* ldt_fw = (const float*)d_in[1];
  const float* lar_fw = (const float*)d_in[2];
  const float* ai_fw  = (const float*)d_in[3];
  const float* C_fw   = (const float*)d_in[4];
  const float* ldt_bw = (const float*)d_in[5];
  const float* lar_bw = (const float*)d_in[6];
  const float* ai_bw  = (const float*)d_in[7];
  const float* C_bw   = (const float*)d_in[8];
  const float* Dskip  = (const float*)d_in[9];
  const float* W      = (const float*)d_in[10];
  const float* bias   = (const float*)d_in[11];
  const float* gamma  = (const float*)d_in[12];
  const float* beta   = (const float*)d_in[13];
  float* out = (float*)d_out;

  // workspace map (bytes):
  //  [0)          ActT   512*65536*2  = 67,108,864
  //  [67108864)   SlocT  16*2*16*256*64*4 = 33,554,432
  //  [100663296)  x16    256*65536*2  = 33,554,432
  //  [134217728)  Vm     2*256*64*256*2 = 16,777,216
  //  [150994944)  P      2*256*256*64*2 = 16,777,216
  //  [167772160)  KK     2*256*512*2  = 524,288
  //  [168296448)  wtb    2*256*64*4   = 131,072
  //  [168427520)  Wb     1,048,576     -> total ~169.5 MB
  //  Act (final [m][ch], 67,108,864 B) aliases [SlocT + x16]; both dead by k_tr2.
  char* wsb = (char*)d_ws;
  bf16*     ActT  = (bf16*)wsb;
  float*    SlocT = (float*)(wsb + 67108864u);
  _Float16* x16   = (_Float16*)(wsb + 100663296u);
  _Float16* Vm    = (_Float16*)(wsb + 134217728u);
  _Float16* P     = (_Float16*)(wsb + 150994944u);
  _Float16* KK    = (_Float16*)(wsb + 167772160u);
  float*    wtb   = (float*)(wsb + 168296448u);
  bf16*     Wb    = (bf16*)(wsb + 168427520u);
  bf16*     Act   = (bf16*)(wsb + 67108864u);   // alias over SlocT+x16

  k_prep<<<dim3(256, 2), dim3(64), 0, stream>>>(
      ldt_fw, lar_fw, ai_fw, C_fw, ldt_bw, lar_bw, ai_bw, C_bw, Vm, P, KK, wtb);
  k_wconv<<<dim3(2048), dim3(256), 0, stream>>>(W, Wb, 1024 * 512);
  k_tr<<<dim3(Mtot / 64, 4), dim3(256), 0, stream>>>(x, x16);
  k_mm1<<<dim3(256, 2), dim3(256), 0, stream>>>(x16, Vm, SlocT);
  k_scan2<<<dim3(Bsz, 2, 4), dim3(256), 0, stream>>>(wtb, SlocT);
  k_mm2<<<dim3(256, 2), dim3(512), 0, stream>>>(x16, KK, P, SlocT, Dskip, ActT);
  k_tr2<<<dim3(Mtot / 64, 8), dim3(256), 0, stream>>>(ActT, Act);
  k_gemm<<<dim3(4096), dim3(256), 0, stream>>>(Act, Wb, bias, out);
  k_ln<<<dim3(Mtot / 4), dim3(256), 0, stream>>>(out, gamma, beta);
}